// Round 6
// baseline (4459.602 us; speedup 1.0000x reference)
//
#include <hip/hip_runtime.h>
#include <math.h>

#define DIM 768
#define NHEADS 12
#define HD 64
#define BATCH 4
#define NQ 1568            // 8*14*14  (T,H,W = 8,14,14)
#define NKV 392            // 8*7*7
#define LN_EPS 1e-6f

typedef unsigned short bfu;

__device__ __forceinline__ float b2f(bfu u) {
    union { unsigned int i; float f; } v; v.i = ((unsigned int)u) << 16; return v.f;
}
__device__ __forceinline__ bfu f2b(float f) {
    union { float f; unsigned int i; } v; v.f = f;
    unsigned int r = v.i + 0x7FFFu + ((v.i >> 16) & 1u);
    return (bfu)(r >> 16);
}
// runtime-dtype load: fl==1 -> f32, fl==0 -> bf16, fl==2 -> zeros tensor
__device__ __forceinline__ float ldf(const void* p, size_t i, int fl) {
    if (fl == 1) return ((const float*)p)[i];
    if (fl == 0) return b2f(((const bfu*)p)[i]);
    return 0.f;
}

struct Ptrs { const void* p[16]; };

// ---- per-tensor dtype probe -----------------------------------------------
// Sample S=min(count,1024) u16s (always within even a bf16-sized buffer).
// zero-tensor: all sampled u16 == 0 -> flag 2 (loads return 0, no OOB risk).
// else: even-indexed u16s are bf16 elements (if bf16) or f32 low-mantissa
// halves (if f32). Biased-exponent band [96,134] holds all magnitudes in
// [5e-10,128] -> bf16 data ~always in band; f32 low halves ~85% out of band.
__global__ __launch_bounds__(64) void probe_kernel(Ptrs ptrs, int* __restrict__ flags) {
    const int cnts[16] = {4816896, 768, 768, 1769472, 2304, 589824, 768,
                          1728, 1728, 64, 64, 64, 64, 1728, 1728, 960};
    int i = blockIdx.x;
    const bfu* u = (const bfu*)ptrs.p[i];
    int S = cnts[i]; if (S > 1024) S = 1024;
    int nz = 0, outb = 0;
    for (int j = threadIdx.x; j < S; j += 64) {
        bfu v = u[j];
        if (v != 0) nz++;
        if ((j & 1) == 0) {
            int e = (v >> 7) & 0xFF;
            if (e < 96 || e > 134) outb++;
        }
    }
    #pragma unroll
    for (int o = 1; o < 64; o <<= 1) { nz += __shfl_xor(nz, o); outb += __shfl_xor(outb, o); }
    if (threadIdx.x == 0) {
        int ne = (S + 1) >> 1;                       // # even-indexed samples
        flags[i] = (nz == 0) ? 2 : ((2 * outb > ne) ? 1 : 0);
    }
}

// ---------------- LayerNorm over DIM=768, one row per block ----------------
__global__ __launch_bounds__(256) void ln_kernel(const void* __restrict__ x,
                                                 const void* __restrict__ w,
                                                 const void* __restrict__ b,
                                                 bfu* __restrict__ out,
                                                 const int* __restrict__ fl) {
    int fx = fl[0], fw = fl[1], fb = fl[2];
    int row = blockIdx.x;
    size_t base = (size_t)row * DIM;
    int t = threadIdx.x;
    float v0 = ldf(x, base + t, fx);
    float v1 = ldf(x, base + t + 256, fx);
    float v2 = ldf(x, base + t + 512, fx);
    float s = v0 + v1 + v2;
    float sq = v0 * v0 + v1 * v1 + v2 * v2;
    #pragma unroll
    for (int o = 1; o < 64; o <<= 1) { s += __shfl_xor(s, o); sq += __shfl_xor(sq, o); }
    __shared__ float ss[4], ssq[4];
    int wid = t >> 6;
    if ((t & 63) == 0) { ss[wid] = s; ssq[wid] = sq; }
    __syncthreads();
    s = ss[0] + ss[1] + ss[2] + ss[3];
    sq = ssq[0] + ssq[1] + ssq[2] + ssq[3];
    float mean = s * (1.0f / DIM);
    float var = sq * (1.0f / DIM) - mean * mean;
    float rs = rsqrtf(fmaxf(var, 0.0f) + LN_EPS);
    bfu* o = out + base;
    o[t]       = f2b((v0 - mean) * rs * ldf(w, t, fw)       + ldf(b, t, fb));
    o[t + 256] = f2b((v1 - mean) * rs * ldf(w, t + 256, fw) + ldf(b, t + 256, fb));
    o[t + 512] = f2b((v2 - mean) * rs * ldf(w, t + 512, fw) + ldf(b, t + 512, fb));
}

// ---- GEMM slice: C(6272x768) = A(bf16) @ W[:, woff:woff+768] + bias -------
// one thread per output element, scalar loads (correctness first)
__global__ __launch_bounds__(256) void gemm_slice_kernel(
    const bfu* __restrict__ A, const void* __restrict__ W,
    const void* __restrict__ bias, bfu* __restrict__ C,
    int woff, int wld, const int* __restrict__ fl, int fwi, int fbi) {
    int fw = fl[fwi], fb = fl[fbi];
    int idx = blockIdx.x * 256 + threadIdx.x;
    int row = idx / DIM;
    int col = idx - row * DIM;
    float acc = ldf(bias, woff + col, fb);
    const bfu* a = A + (size_t)row * DIM;
    for (int k = 0; k < DIM; ++k)
        acc += b2f(a[k]) * ldf(W, (size_t)k * wld + woff + col, fw);
    C[(size_t)row * DIM + col] = f2b(acc);
}

// ---- proj GEMM: f32 output to d_out ---------------------------------------
__global__ __launch_bounds__(256) void gemm_proj_kernel(
    const bfu* __restrict__ A, const void* __restrict__ W,
    const void* __restrict__ bias, float* __restrict__ C,
    const int* __restrict__ fl) {
    int fw = fl[5], fb = fl[6];
    int idx = blockIdx.x * 256 + threadIdx.x;
    int row = idx / DIM;
    int col = idx - row * DIM;
    float acc = ldf(bias, col, fb);
    const bfu* a = A + (size_t)row * DIM;
    for (int k = 0; k < DIM; ++k)
        acc += b2f(a[k]) * ldf(W, (size_t)k * DIM + col, fw);
    C[(size_t)row * DIM + col] = acc;
}

// ------------- depthwise conv3d pool (3x3x3, stride 1,2,2, pad 1) + LN -----
// one wave per output position (64 lanes = channels); 4 positions/block
__global__ __launch_bounds__(256) void pool_ln_kernel(
    const bfu* __restrict__ kv, const void* __restrict__ pw,
    const void* __restrict__ lw, const void* __restrict__ lb,
    bfu* __restrict__ out, const int* __restrict__ fl,
    int fpi, int fwi, int fbi) {
    int fp = fl[fpi], fw = fl[fwi], fb = fl[fbi];
    int p = blockIdx.x * 4 + (threadIdx.x >> 6);
    int lane = threadIdx.x & 63;
    int b = p / (NHEADS * NKV);
    int rem = p % (NHEADS * NKV);
    int h = rem / NKV;
    int kpos = rem % NKV;
    int kt = kpos / 49;
    int r2 = kpos % 49;
    int kh = r2 / 7;
    int kw = r2 % 7;
    float acc = 0.f;
    #pragma unroll
    for (int dt = 0; dt < 3; ++dt) {
        int tt = kt + dt - 1;
        if (tt < 0 || tt >= 8) continue;
        #pragma unroll
        for (int dh = 0; dh < 3; ++dh) {
            int hh = kh * 2 + dh - 1;
            if (hh < 0 || hh >= 14) continue;
            #pragma unroll
            for (int dw = 0; dw < 3; ++dw) {
                int ww = kw * 2 + dw - 1;
                if (ww < 0 || ww >= 14) continue;
                int n = (tt * 14 + hh) * 14 + ww;
                float in = b2f(kv[(size_t)(b * NQ + n) * DIM + h * HD + lane]);
                acc += in * ldf(pw, lane * 27 + dt * 9 + dh * 3 + dw, fp);
            }
        }
    }
    float s = acc, sq = acc * acc;
    #pragma unroll
    for (int o = 1; o < 64; o <<= 1) { s += __shfl_xor(s, o); sq += __shfl_xor(sq, o); }
    float mean = s * (1.0f / 64.0f);
    float var = sq * (1.0f / 64.0f) - mean * mean;
    float rs = rsqrtf(fmaxf(var, 0.0f) + LN_EPS);
    out[(size_t)p * HD + lane] = f2b((acc - mean) * rs * ldf(lw, lane, fw) + ldf(lb, lane, fb));
}

// ---- fused attention: one 64-thread block per (b,h,q-row) -----------------
__global__ __launch_bounds__(64) void attn_kernel(
    const bfu* __restrict__ qb, const bfu* __restrict__ kp,
    const bfu* __restrict__ vp, const void* __restrict__ rpt,
    const void* __restrict__ rph, const void* __restrict__ rpw,
    bfu* __restrict__ ao, const int* __restrict__ fl) {
    int fh = fl[13], fw = fl[14], ft = fl[15];
    int blk = blockIdx.x;
    int nq = blk % NQ;
    int bh = blk / NQ;                 // b*NHEADS + h
    int h = bh % NHEADS;
    int b = bh / NHEADS;
    int lane = threadIdx.x;

    __shared__ float q[HD];
    __shared__ float bias[22];
    __shared__ float P[NKV];

    q[lane] = b2f(qb[(size_t)(b * NQ + nq) * DIM + h * HD + lane]);
    __syncthreads();

    int tq = nq / 196, hq = (nq % 196) / 14, wq = nq % 14;
    if (lane < 22) {
        const void* R; int ridx, rf;
        if (lane < 8)       { R = rpt; ridx = tq - lane + 7;            rf = ft; }
        else if (lane < 15) { R = rph; ridx = hq - 2 * (lane - 8) + 12; rf = fh; }
        else                { R = rpw; ridx = wq - 2 * (lane - 15) + 12; rf = fw; }
        float d = 0.f;
        for (int c = 0; c < HD; ++c) d += q[c] * ldf(R, (size_t)ridx * HD + c, rf);
        bias[lane] = d;
    }
    __syncthreads();

    const bfu* kb = kp + (size_t)bh * NKV * HD;
    float mx = -1e30f;
    for (int kj = lane; kj < NKV; kj += 64) {
        const bfu* kr = kb + (size_t)kj * HD;
        float d = 0.f;
        for (int c = 0; c < HD; ++c) d += q[c] * b2f(kr[c]);
        int kt = kj / 49, r2 = kj % 49;
        float sval = 0.125f * d + bias[kt] + bias[8 + r2 / 7] + bias[15 + r2 % 7];
        P[kj] = sval;
        mx = fmaxf(mx, sval);
    }
    #pragma unroll
    for (int o = 1; o < 64; o <<= 1) mx = fmaxf(mx, __shfl_xor(mx, o));
    __syncthreads();

    float sum = 0.f;
    for (int kj = lane; kj < NKV; kj += 64) {
        float e = expf(P[kj] - mx);
        P[kj] = e;
        sum += e;
    }
    #pragma unroll
    for (int o = 1; o < 64; o <<= 1) sum += __shfl_xor(sum, o);
    float inv = 1.f / sum;
    __syncthreads();

    const bfu* vb = vp + (size_t)bh * NKV * HD;
    float acc = 0.f;
    for (int kj = 0; kj < NKV; ++kj)
        acc += P[kj] * b2f(vb[(size_t)kj * HD + lane]);
    ao[(size_t)(b * NQ + nq) * DIM + h * HD + lane] = f2b(acc * inv + q[lane]);
}

extern "C" void kernel_launch(void* const* d_in, const int* in_sizes, int n_in,
                              void* d_out, int out_size, void* d_ws, size_t ws_size,
                              hipStream_t stream) {
    Ptrs ptrs;
    for (int i = 0; i < 16; ++i) ptrs.p[i] = d_in[i];
    const void* x      = d_in[0];
    const void* ln_w   = d_in[1];
    const void* ln_b   = d_in[2];
    const void* qkv_w  = d_in[3];
    const void* qkv_b  = d_in[4];
    const void* proj_w = d_in[5];
    const void* proj_b = d_in[6];
    const void* poolk_w = d_in[7];
    const void* poolv_w = d_in[8];
    const void* rph    = d_in[13];
    const void* rpw    = d_in[14];
    const void* rpt    = d_in[15];

    // ws layout (bfu units). Peak = 24,084,544 bytes <= confirmed ws floor.
    bfu* ws = (bfu*)d_ws;
    bfu* A  = ws;                       // 4,816,896 elems: xn, later ao
    bfu* Bf = ws + 4816896;             // 4,816,896: k-proj / v-proj / q-proj
    bfu* kp = ws + 9633792;             // 1,204,224
    bfu* vp = ws + 10838016;            // 1,204,224
    int* flags = (int*)(ws + 12042240); // 64 bytes
    float* out = (float*)d_out;

    probe_kernel<<<16, 64, 0, stream>>>(ptrs, flags);

    // xn = LN(x)
    ln_kernel<<<BATCH * NQ, 256, 0, stream>>>(x, ln_w, ln_b, A, flags);

    // k = xn @ Wk -> Bf ; pool+LN -> kp
    gemm_slice_kernel<<<18816, 256, 0, stream>>>(A, qkv_w, qkv_b, Bf, DIM, 3 * DIM, flags, 3, 4);
    pool_ln_kernel<<<4704, 256, 0, stream>>>(Bf, poolk_w, d_in[9], d_in[10], kp, flags, 7, 9, 10);

    // v = xn @ Wv -> Bf ; pool+LN -> vp
    gemm_slice_kernel<<<18816, 256, 0, stream>>>(A, qkv_w, qkv_b, Bf, 2 * DIM, 3 * DIM, flags, 3, 4);
    pool_ln_kernel<<<4704, 256, 0, stream>>>(Bf, poolv_w, d_in[11], d_in[12], vp, flags, 8, 11, 12);

    // q = xn @ Wq -> Bf (xn dead afterwards)
    gemm_slice_kernel<<<18816, 256, 0, stream>>>(A, qkv_w, qkv_b, Bf, 0, 3 * DIM, flags, 3, 4);

    // attention (+residual) -> A
    attn_kernel<<<BATCH * NHEADS * NQ, 64, 0, stream>>>(Bf, kp, vp, rpt, rph, rpw, A, flags);

    // out = A @ proj_w + proj_b  (f32 out per harness doc)
    gemm_proj_kernel<<<18816, 256, 0, stream>>>(A, proj_w, proj_b, out, flags);
}

// Round 7
// 1132.953 us; speedup vs baseline: 3.9363x; 3.9363x over previous
//
#include <hip/hip_runtime.h>
#include <math.h>

#define DIM 768
#define NHEADS 12
#define HD 64
#define BATCH 4
#define NQ 1568            // 8*14*14  (T,H,W = 8,14,14)
#define NKV 392            // 8*7*7
#define LN_EPS 1e-6f

typedef unsigned short bfu;
typedef __attribute__((ext_vector_type(8))) short bf16x8;
typedef __attribute__((ext_vector_type(4))) float f32x4;

__device__ __forceinline__ float b2f(bfu u) {
    union { unsigned int i; float f; } v; v.i = ((unsigned int)u) << 16; return v.f;
}
__device__ __forceinline__ bfu f2b(float f) {
    union { float f; unsigned int i; } v; v.f = f;
    unsigned int r = v.i + 0x7FFFu + ((v.i >> 16) & 1u);
    return (bfu)(r >> 16);
}
// runtime-dtype load: fl==1 -> f32, fl==0 -> bf16, fl==2 -> zeros tensor
__device__ __forceinline__ float ldf(const void* p, size_t i, int fl) {
    if (fl == 1) return ((const float*)p)[i];
    if (fl == 0) return b2f(((const bfu*)p)[i]);
    return 0.f;
}

struct Ptrs { const void* p[16]; };

// ---- per-tensor dtype probe (unchanged from round 6, verified working) ----
__global__ __launch_bounds__(64) void probe_kernel(Ptrs ptrs, int* __restrict__ flags) {
    const int cnts[16] = {4816896, 768, 768, 1769472, 2304, 589824, 768,
                          1728, 1728, 64, 64, 64, 64, 1728, 1728, 960};
    int i = blockIdx.x;
    const bfu* u = (const bfu*)ptrs.p[i];
    int S = cnts[i]; if (S > 1024) S = 1024;
    int nz = 0, outb = 0;
    for (int j = threadIdx.x; j < S; j += 64) {
        bfu v = u[j];
        if (v != 0) nz++;
        if ((j & 1) == 0) {
            int e = (v >> 7) & 0xFF;
            if (e < 96 || e > 134) outb++;
        }
    }
    #pragma unroll
    for (int o = 1; o < 64; o <<= 1) { nz += __shfl_xor(nz, o); outb += __shfl_xor(outb, o); }
    if (threadIdx.x == 0) {
        int ne = (S + 1) >> 1;
        flags[i] = (nz == 0) ? 2 : ((2 * outb > ne) ? 1 : 0);
    }
}

// ---------------- LayerNorm over DIM=768, one row per block ----------------
__global__ __launch_bounds__(256) void ln_kernel(const void* __restrict__ x,
                                                 const void* __restrict__ w,
                                                 const void* __restrict__ b,
                                                 bfu* __restrict__ out,
                                                 const int* __restrict__ fl) {
    int fx = fl[0], fw = fl[1], fb = fl[2];
    int row = blockIdx.x;
    size_t base = (size_t)row * DIM;
    int t = threadIdx.x;
    float v0 = ldf(x, base + t, fx);
    float v1 = ldf(x, base + t + 256, fx);
    float v2 = ldf(x, base + t + 512, fx);
    float s = v0 + v1 + v2;
    float sq = v0 * v0 + v1 * v1 + v2 * v2;
    #pragma unroll
    for (int o = 1; o < 64; o <<= 1) { s += __shfl_xor(s, o); sq += __shfl_xor(sq, o); }
    __shared__ float ss[4], ssq[4];
    int wid = t >> 6;
    if ((t & 63) == 0) { ss[wid] = s; ssq[wid] = sq; }
    __syncthreads();
    s = ss[0] + ss[1] + ss[2] + ss[3];
    sq = ssq[0] + ssq[1] + ssq[2] + ssq[3];
    float mean = s * (1.0f / DIM);
    float var = sq * (1.0f / DIM) - mean * mean;
    float rs = rsqrtf(fmaxf(var, 0.0f) + LN_EPS);
    bfu* o = out + base;
    o[t]       = f2b((v0 - mean) * rs * ldf(w, t, fw)       + ldf(b, t, fb));
    o[t + 256] = f2b((v1 - mean) * rs * ldf(w, t + 256, fw) + ldf(b, t + 256, fb));
    o[t + 512] = f2b((v2 - mean) * rs * ldf(w, t + 512, fw) + ldf(b, t + 512, fb));
}

// ---- MFMA GEMM: C(6272 x 768) = A(bf16) @ W[:, woff:woff+768] + bias ------
template<bool F32OUT>
__global__ __launch_bounds__(256) void gemm_mfma_kernel(
    const bfu* __restrict__ A, const void* __restrict__ W,
    const void* __restrict__ bias, void* __restrict__ Cout,
    int woff, int wld, const int* __restrict__ fl, int fwi, int fbi) {
    int fw = fl[fwi], fb = fl[fbi];
    __shared__ bfu As[4096];              // 8 KB: [8 mgrp][4 kgrp][16 r][8 j]
    int t = threadIdx.x;
    int l = t & 63;
    int wv = t >> 6;
    int wr = wv >> 1, wc = wv & 1;        // wave tile origin (wr*64, wc*64)
    int g = l >> 4, r = l & 15;
    int brow = blockIdx.y * 128;
    int bcol = blockIdx.x * 128;

    f32x4 acc[4][4];
    #pragma unroll
    for (int m = 0; m < 4; ++m)
        #pragma unroll
        for (int n = 0; n < 4; ++n)
            #pragma unroll
            for (int q = 0; q < 4; ++q) acc[m][n][q] = 0.f;

    int srow = t >> 1, sseg = t & 1;
    const bfu* agp = A + (size_t)(brow + srow) * DIM + sseg * 16;
    int w0 = (((srow >> 4) * 4 + sseg * 2 + 0) * 16 + (srow & 15)) * 8;
    int w1 = (((srow >> 4) * 4 + sseg * 2 + 1) * 16 + (srow & 15)) * 8;

    int gcol = bcol + wc * 64 + r;        // + n*16 per fragment

    for (int k0 = 0; k0 < DIM; k0 += 32) {
        bf16x8 av0 = *(const bf16x8*)(agp + k0);
        bf16x8 av1 = *(const bf16x8*)(agp + k0 + 8);
        *(bf16x8*)&As[w0] = av0;
        *(bf16x8*)&As[w1] = av1;
        __syncthreads();

        bf16x8 bfrag[4];
        int krow = k0 + g * 8;
        #pragma unroll
        for (int n = 0; n < 4; ++n) {
            size_t cb = (size_t)krow * wld + woff + gcol + n * 16;
            #pragma unroll
            for (int j = 0; j < 8; ++j)
                bfrag[n][j] = (short)f2b(ldf(W, cb + (size_t)j * wld, fw));
        }
        bf16x8 afrag[4];
        #pragma unroll
        for (int m = 0; m < 4; ++m)
            afrag[m] = *(const bf16x8*)&As[(((wr * 4 + m) * 4 + g) * 16 + r) * 8];

        #pragma unroll
        for (int m = 0; m < 4; ++m)
            #pragma unroll
            for (int n = 0; n < 4; ++n)
                acc[m][n] = __builtin_amdgcn_mfma_f32_16x16x32_bf16(
                    afrag[m], bfrag[n], acc[m][n], 0, 0, 0);
        __syncthreads();
    }

    float bv[4];
    #pragma unroll
    for (int n = 0; n < 4; ++n) bv[n] = ldf(bias, woff + gcol + n * 16, fb);
    #pragma unroll
    for (int m = 0; m < 4; ++m) {
        #pragma unroll
        for (int n = 0; n < 4; ++n) {
            #pragma unroll
            for (int i = 0; i < 4; ++i) {
                float v = acc[m][n][i] + bv[n];
                size_t row = brow + wr * 64 + m * 16 + g * 4 + i;
                size_t col = bcol + wc * 64 + n * 16 + r;
                if (F32OUT) ((float*)Cout)[row * DIM + col] = v;
                else        ((bfu*)Cout)[row * DIM + col] = f2b(v);
            }
        }
    }
}

// ------------- depthwise conv3d pool (3x3x3, stride 1,2,2, pad 1) + LN -----
__global__ __launch_bounds__(256) void pool_ln_kernel(
    const bfu* __restrict__ kv, const void* __restrict__ pw,
    const void* __restrict__ lw, const void* __restrict__ lb,
    bfu* __restrict__ out, const int* __restrict__ fl,
    int fpi, int fwi, int fbi) {
    int fp = fl[fpi], fw = fl[fwi], fb = fl[fbi];
    int p = blockIdx.x * 4 + (threadIdx.x >> 6);
    int lane = threadIdx.x & 63;
    int b = p / (NHEADS * NKV);
    int rem = p % (NHEADS * NKV);
    int h = rem / NKV;
    int kpos = rem % NKV;
    int kt = kpos / 49;
    int r2 = kpos % 49;
    int kh = r2 / 7;
    int kw = r2 % 7;
    float acc = 0.f;
    #pragma unroll
    for (int dt = 0; dt < 3; ++dt) {
        int tt = kt + dt - 1;
        if (tt < 0 || tt >= 8) continue;
        #pragma unroll
        for (int dh = 0; dh < 3; ++dh) {
            int hh = kh * 2 + dh - 1;
            if (hh < 0 || hh >= 14) continue;
            #pragma unroll
            for (int dw = 0; dw < 3; ++dw) {
                int ww = kw * 2 + dw - 1;
                if (ww < 0 || ww >= 14) continue;
                int n = (tt * 14 + hh) * 14 + ww;
                float in = b2f(kv[(size_t)(b * NQ + n) * DIM + h * HD + lane]);
                acc += in * ldf(pw, lane * 27 + dt * 9 + dh * 3 + dw, fp);
            }
        }
    }
    float s = acc, sq = acc * acc;
    #pragma unroll
    for (int o = 1; o < 64; o <<= 1) { s += __shfl_xor(s, o); sq += __shfl_xor(sq, o); }
    float mean = s * (1.0f / 64.0f);
    float var = sq * (1.0f / 64.0f) - mean * mean;
    float rs = rsqrtf(fmaxf(var, 0.0f) + LN_EPS);
    out[(size_t)p * HD + lane] = f2b((acc - mean) * rs * ldf(lw, lane, fw) + ldf(lb, lane, fb));
}

// ---- fused attention: 256-thread block = 4 waves, one q-row per wave ------
__global__ __launch_bounds__(256) void attn_kernel(
    const bfu* __restrict__ qb, const bfu* __restrict__ kp,
    const bfu* __restrict__ vp, const void* __restrict__ rpt,
    const void* __restrict__ rph, const void* __restrict__ rpw,
    bfu* __restrict__ ao, const int* __restrict__ fl) {
    int fh = fl[13], fw = fl[14], ft = fl[15];
    int wid = threadIdx.x >> 6;
    int lane = threadIdx.x & 63;
    int blk = blockIdx.x;
    int qt = blk % (NQ / 4);
    int bh = blk / (NQ / 4);          // b*NHEADS + h
    int h = bh % NHEADS;
    int b = bh / NHEADS;
    int nq = qt * 4 + wid;

    __shared__ float q[4][HD];
    __shared__ float bias[4][22];
    __shared__ float P[4][NKV];

    float qv = b2f(qb[(size_t)(b * NQ + nq) * DIM + h * HD + lane]);
    q[wid][lane] = qv;
    __syncthreads();

    float4 qreg[16];
    #pragma unroll
    for (int i = 0; i < 16; ++i) qreg[i] = *(const float4*)&q[wid][i * 4];

    int tq = nq / 196, hq = (nq % 196) / 14, wq = nq % 14;
    if (lane < 22) {
        const void* R; int ridx, rf;
        if (lane < 8)       { R = rpt; ridx = tq - lane + 7;             rf = ft; }
        else if (lane < 15) { R = rph; ridx = hq - 2 * (lane - 8) + 12;  rf = fh; }
        else                { R = rpw; ridx = wq - 2 * (lane - 15) + 12; rf = fw; }
        size_t rb = (size_t)ridx * HD;
        float d = 0.f;
        #pragma unroll
        for (int i = 0; i < 16; ++i) {
            float4 qq = qreg[i];
            d += qq.x * ldf(R, rb + i * 4 + 0, rf) + qq.y * ldf(R, rb + i * 4 + 1, rf)
               + qq.z * ldf(R, rb + i * 4 + 2, rf) + qq.w * ldf(R, rb + i * 4 + 3, rf);
        }
        bias[wid][lane] = d;
    }
    __syncthreads();

    const bfu* kb = kp + (size_t)bh * NKV * HD;
    float mx = -1e30f;
    for (int kj = lane; kj < NKV; kj += 64) {
        const bfu* kr = kb + (size_t)kj * HD;
        float d = 0.f;
        #pragma unroll
        for (int i = 0; i < 16; ++i) {
            ushort4 u = *(const ushort4*)(kr + i * 4);
            float4 qq = qreg[i];
            d += qq.x * b2f(u.x) + qq.y * b2f(u.y) + qq.z * b2f(u.z) + qq.w * b2f(u.w);
        }
        int kt = kj / 49, r2 = kj % 49;
        float sval = 0.125f * d + bias[wid][kt] + bias[wid][8 + r2 / 7] + bias[wid][15 + r2 % 7];
        P[wid][kj] = sval;
        mx = fmaxf(mx, sval);
    }
    #pragma unroll
    for (int o = 1; o < 64; o <<= 1) mx = fmaxf(mx, __shfl_xor(mx, o));

    float sum = 0.f;
    for (int kj = lane; kj < NKV; kj += 64) {
        float e = expf(P[wid][kj] - mx);
        P[wid][kj] = e;
        sum += e;
    }
    #pragma unroll
    for (int o = 1; o < 64; o <<= 1) sum += __shfl_xor(sum, o);
    float inv = 1.f / sum;
    __syncthreads();

    const bfu* vb = vp + (size_t)bh * NKV * HD;
    float acc = 0.f;
    for (int kj = 0; kj < NKV; ++kj)
        acc += P[wid][kj] * b2f(vb[(size_t)kj * HD + lane]);
    ao[(size_t)(b * NQ + nq) * DIM + h * HD + lane] = f2b(acc * inv + qv);
}

extern "C" void kernel_launch(void* const* d_in, const int* in_sizes, int n_in,
                              void* d_out, int out_size, void* d_ws, size_t ws_size,
                              hipStream_t stream) {
    Ptrs ptrs;
    for (int i = 0; i < 16; ++i) ptrs.p[i] = d_in[i];
    const void* x      = d_in[0];
    const void* ln_w   = d_in[1];
    const void* ln_b   = d_in[2];
    const void* qkv_w  = d_in[3];
    const void* qkv_b  = d_in[4];
    const void* proj_w = d_in[5];
    const void* proj_b = d_in[6];
    const void* poolk_w = d_in[7];
    const void* poolv_w = d_in[8];
    const void* rph    = d_in[13];
    const void* rpw    = d_in[14];
    const void* rpt    = d_in[15];

    bfu* ws = (bfu*)d_ws;
    bfu* A  = ws;                       // 4,816,896: xn, later attention out
    bfu* Bf = ws + 4816896;             // 4,816,896: k / v / q projections
    bfu* kp = ws + 9633792;             // 1,204,224
    bfu* vp = ws + 10838016;            // 1,204,224
    int* flags = (int*)(ws + 12042240); // 64 bytes
    float* out = (float*)d_out;

    probe_kernel<<<16, 64, 0, stream>>>(ptrs, flags);

    ln_kernel<<<BATCH * NQ, 256, 0, stream>>>(x, ln_w, ln_b, A, flags);

    dim3 ggrid(6, 49);
    gemm_mfma_kernel<false><<<ggrid, 256, 0, stream>>>(A, qkv_w, qkv_b, Bf, DIM, 3 * DIM, flags, 3, 4);
    pool_ln_kernel<<<4704, 256, 0, stream>>>(Bf, poolk_w, d_in[9], d_in[10], kp, flags, 7, 9, 10);

    gemm_mfma_kernel<false><<<ggrid, 256, 0, stream>>>(A, qkv_w, qkv_b, Bf, 2 * DIM, 3 * DIM, flags, 3, 4);
    pool_ln_kernel<<<4704, 256, 0, stream>>>(Bf, poolv_w, d_in[11], d_in[12], vp, flags, 8, 11, 12);

    gemm_mfma_kernel<false><<<ggrid, 256, 0, stream>>>(A, qkv_w, qkv_b, Bf, 0, 3 * DIM, flags, 3, 4);

    attn_kernel<<<BATCH * NHEADS * (NQ / 4), 256, 0, stream>>>(Bf, kp, vp, rpt, rph, rpw, A, flags);

    gemm_mfma_kernel<true><<<ggrid, 256, 0, stream>>>(A, proj_w, proj_b, out, 0, DIM, flags, 5, 6);
}

// Round 9
// 669.487 us; speedup vs baseline: 6.6612x; 1.6923x over previous
//
#include <hip/hip_runtime.h>
#include <math.h>

#define DIM 768
#define NHEADS 12
#define HD 64
#define BATCH 4
#define NQ 1568            // 8*14*14  (T,H,W = 8,14,14)
#define NKV 392            // 8*7*7
#define LN_EPS 1e-6f

typedef unsigned short bfu;
typedef __attribute__((ext_vector_type(8))) short bf16x8;
typedef __attribute__((ext_vector_type(4))) float f32x4;

__device__ __forceinline__ float b2f(bfu u) {
    union { unsigned int i; float f; } v; v.i = ((unsigned int)u) << 16; return v.f;
}
__device__ __forceinline__ bfu f2b(float f) {
    union { float f; unsigned int i; } v; v.f = f;
    unsigned int r = v.i + 0x7FFFu + ((v.i >> 16) & 1u);
    return (bfu)(r >> 16);
}
// runtime-dtype load: fl==1 -> f32, fl==0 -> bf16, fl==2 -> zeros tensor
__device__ __forceinline__ float ldf(const void* p, size_t i, int fl) {
    if (fl == 1) return ((const float*)p)[i];
    if (fl == 0) return b2f(((const bfu*)p)[i]);
    return 0.f;
}

struct Ptrs { const void* p[16]; };

// ---- per-tensor dtype probe (verified working) ----------------------------
__global__ __launch_bounds__(64) void probe_kernel(Ptrs ptrs, int* __restrict__ flags) {
    const int cnts[16] = {4816896, 768, 768, 1769472, 2304, 589824, 768,
                          1728, 1728, 64, 64, 64, 64, 1728, 1728, 960};
    int i = blockIdx.x;
    const bfu* u = (const bfu*)ptrs.p[i];
    int S = cnts[i]; if (S > 1024) S = 1024;
    int nz = 0, outb = 0;
    for (int j = threadIdx.x; j < S; j += 64) {
        bfu v = u[j];
        if (v != 0) nz++;
        if ((j & 1) == 0) {
            int e = (v >> 7) & 0xFF;
            if (e < 96 || e > 134) outb++;
        }
    }
    #pragma unroll
    for (int o = 1; o < 64; o <<= 1) { nz += __shfl_xor(nz, o); outb += __shfl_xor(outb, o); }
    if (threadIdx.x == 0) {
        int ne = (S + 1) >> 1;
        flags[i] = (nz == 0) ? 2 : ((2 * outb > ne) ? 1 : 0);
    }
}

// ---------------- LayerNorm over DIM=768, one row per block ----------------
__global__ __launch_bounds__(256) void ln_kernel(const void* __restrict__ x,
                                                 const void* __restrict__ w,
                                                 const void* __restrict__ b,
                                                 bfu* __restrict__ out,
                                                 const int* __restrict__ fl) {
    int fx = fl[0], fw = fl[1], fb = fl[2];
    int row = blockIdx.x;
    size_t base = (size_t)row * DIM;
    int t = threadIdx.x;
    float v0 = ldf(x, base + t, fx);
    float v1 = ldf(x, base + t + 256, fx);
    float v2 = ldf(x, base + t + 512, fx);
    float s = v0 + v1 + v2;
    float sq = v0 * v0 + v1 * v1 + v2 * v2;
    #pragma unroll
    for (int o = 1; o < 64; o <<= 1) { s += __shfl_xor(s, o); sq += __shfl_xor(sq, o); }
    __shared__ float ss[4], ssq[4];
    int wid = t >> 6;
    if ((t & 63) == 0) { ss[wid] = s; ssq[wid] = sq; }
    __syncthreads();
    s = ss[0] + ss[1] + ss[2] + ss[3];
    sq = ssq[0] + ssq[1] + ssq[2] + ssq[3];
    float mean = s * (1.0f / DIM);
    float var = sq * (1.0f / DIM) - mean * mean;
    float rs = rsqrtf(fmaxf(var, 0.0f) + LN_EPS);
    bfu* o = out + base;
    o[t]       = f2b((v0 - mean) * rs * ldf(w, t, fw)       + ldf(b, t, fb));
    o[t + 256] = f2b((v1 - mean) * rs * ldf(w, t + 256, fw) + ldf(b, t + 256, fb));
    o[t + 512] = f2b((v2 - mean) * rs * ldf(w, t + 512, fw) + ldf(b, t + 512, fb));
}

// ---- MFMA GEMM: C(6272 x 768) = A(bf16) @ W[:, woff:woff+768] + bias ------
// grid(49 row-tiles, 6 col-tiles): consecutive blocks share the W col-slab (L2)
template<bool F32OUT>
__global__ __launch_bounds__(256) void gemm_mfma_kernel(
    const bfu* __restrict__ A, const void* __restrict__ W,
    const void* __restrict__ bias, void* __restrict__ Cout,
    int woff, int wld, const int* __restrict__ fl, int fwi, int fbi) {
    int fw = fl[fwi], fb = fl[fbi];
    __shared__ bfu As[4096];              // 8 KB: [8 mgrp][4 kgrp][16 r][8 j]
    int t = threadIdx.x;
    int l = t & 63;
    int wv = t >> 6;
    int wr = wv >> 1, wc = wv & 1;
    int g = l >> 4, r = l & 15;
    int brow = blockIdx.x * 128;
    int bcol = blockIdx.y * 128;

    f32x4 acc[4][4];
    #pragma unroll
    for (int m = 0; m < 4; ++m)
        #pragma unroll
        for (int n = 0; n < 4; ++n)
            #pragma unroll
            for (int q = 0; q < 4; ++q) acc[m][n][q] = 0.f;

    int srow = t >> 1, sseg = t & 1;
    const bfu* agp = A + (size_t)(brow + srow) * DIM + sseg * 16;
    int w0 = (((srow >> 4) * 4 + sseg * 2 + 0) * 16 + (srow & 15)) * 8;
    int w1 = (((srow >> 4) * 4 + sseg * 2 + 1) * 16 + (srow & 15)) * 8;

    int gcol = bcol + wc * 64 + r;

    for (int k0 = 0; k0 < DIM; k0 += 32) {
        bf16x8 av0 = *(const bf16x8*)(agp + k0);
        bf16x8 av1 = *(const bf16x8*)(agp + k0 + 8);
        *(bf16x8*)&As[w0] = av0;
        *(bf16x8*)&As[w1] = av1;
        __syncthreads();

        bf16x8 bfrag[4];
        int krow = k0 + g * 8;
        #pragma unroll
        for (int n = 0; n < 4; ++n) {
            size_t cb = (size_t)krow * wld + woff + gcol + n * 16;
            #pragma unroll
            for (int j = 0; j < 8; ++j)
                bfrag[n][j] = (short)f2b(ldf(W, cb + (size_t)j * wld, fw));
        }
        bf16x8 afrag[4];
        #pragma unroll
        for (int m = 0; m < 4; ++m)
            afrag[m] = *(const bf16x8*)&As[(((wr * 4 + m) * 4 + g) * 16 + r) * 8];

        #pragma unroll
        for (int m = 0; m < 4; ++m)
            #pragma unroll
            for (int n = 0; n < 4; ++n)
                acc[m][n] = __builtin_amdgcn_mfma_f32_16x16x32_bf16(
                    afrag[m], bfrag[n], acc[m][n], 0, 0, 0);
        __syncthreads();
    }

    float bv[4];
    #pragma unroll
    for (int n = 0; n < 4; ++n) bv[n] = ldf(bias, woff + gcol + n * 16, fb);
    #pragma unroll
    for (int m = 0; m < 4; ++m) {
        #pragma unroll
        for (int n = 0; n < 4; ++n) {
            #pragma unroll
            for (int i = 0; i < 4; ++i) {
                float v = acc[m][n][i] + bv[n];
                size_t row = brow + wr * 64 + m * 16 + g * 4 + i;
                size_t col = bcol + wc * 64 + n * 16 + r;
                if (F32OUT) ((float*)Cout)[row * DIM + col] = v;
                else        ((bfu*)Cout)[row * DIM + col] = f2b(v);
            }
        }
    }
}

// ------------- depthwise conv3d pool (3x3x3, stride 1,2,2, pad 1) + LN -----
// TR=false: out[(bh*NKV + kpos)*64 + lane]   (K layout [bh][kj][d])
// TR=true : out[(bh*64 + lane)*NKV + kpos]   (V^T layout [bh][d][kj])
template<bool TR>
__global__ __launch_bounds__(256) void pool_ln_kernel(
    const bfu* __restrict__ kv, const void* __restrict__ pw,
    const void* __restrict__ lw, const void* __restrict__ lb,
    bfu* __restrict__ out, const int* __restrict__ fl,
    int fpi, int fwi, int fbi) {
    int fp = fl[fpi], fw = fl[fwi], fb = fl[fbi];
    int p = blockIdx.x * 4 + (threadIdx.x >> 6);
    int lane = threadIdx.x & 63;
    int b = p / (NHEADS * NKV);
    int rem = p % (NHEADS * NKV);
    int h = rem / NKV;
    int kpos = rem % NKV;
    int kt = kpos / 49;
    int r2 = kpos % 49;
    int kh = r2 / 7;
    int kw = r2 % 7;
    float acc = 0.f;
    #pragma unroll
    for (int dt = 0; dt < 3; ++dt) {
        int tt = kt + dt - 1;
        if (tt < 0 || tt >= 8) continue;
        #pragma unroll
        for (int dh = 0; dh < 3; ++dh) {
            int hh = kh * 2 + dh - 1;
            if (hh < 0 || hh >= 14) continue;
            #pragma unroll
            for (int dw = 0; dw < 3; ++dw) {
                int ww = kw * 2 + dw - 1;
                if (ww < 0 || ww >= 14) continue;
                int n = (tt * 14 + hh) * 14 + ww;
                float in = b2f(kv[(size_t)(b * NQ + n) * DIM + h * HD + lane]);
                acc += in * ldf(pw, lane * 27 + dt * 9 + dh * 3 + dw, fp);
            }
        }
    }
    float s = acc, sq = acc * acc;
    #pragma unroll
    for (int o = 1; o < 64; o <<= 1) { s += __shfl_xor(s, o); sq += __shfl_xor(sq, o); }
    float mean = s * (1.0f / 64.0f);
    float var = sq * (1.0f / 64.0f) - mean * mean;
    float rs = rsqrtf(fmaxf(var, 0.0f) + LN_EPS);
    float v = (acc - mean) * rs * ldf(lw, lane, fw) + ldf(lb, lane, fb);
    int bh = b * NHEADS + h;
    if (TR) out[((size_t)bh * HD + lane) * NKV + kpos] = f2b(v);
    else    out[((size_t)bh * NKV + kpos) * HD + lane] = f2b(v);
}

// ---- MFMA flash attention: block = 4 waves x 16 q-rows, kv tiles of 32 ----
__global__ __launch_bounds__(256) void attn_mfma_kernel(
    const bfu* __restrict__ qb, const bfu* __restrict__ kp,
    const bfu* __restrict__ vt, const void* __restrict__ rpt,
    const void* __restrict__ rph, const void* __restrict__ rpw,
    bfu* __restrict__ ao, const int* __restrict__ fl) {
    int fh = fl[13], fwF = fl[14], ft = fl[15];
    __shared__ float bsT[64][8];
    __shared__ float bsD[64][14];
    __shared__ float bsHW[64][52];
    __shared__ bfu   Pl[4][16][40];   // per-wave P transpose tile (stride 40)

    int t = threadIdx.x;
    int l = t & 63, w = t >> 6;
    int g = l >> 4, r = l & 15;
    int blk = blockIdx.x;
    int qt = blk % 25, bh = blk / 25;
    int h = bh % NHEADS, b = bh / NHEADS;
    int rowbase = qt * 64;

    // ---- bias phase: 22 rel-pos dots per q-row, cooperative ----
    for (int id = t; id < 64 * 22; id += 256) {
        int rr = id / 22, idx = id - rr * 22;
        int nq = rowbase + rr;
        if (nq < NQ) {
            int tq = nq / 196, hq = (nq % 196) / 14, wq = nq % 14;
            const void* R; int ridx, rf;
            if (idx < 8)       { R = rpt; ridx = tq - idx + 7;             rf = ft; }
            else if (idx < 15) { R = rph; ridx = hq - 2 * (idx - 8) + 12;  rf = fh; }
            else               { R = rpw; ridx = wq - 2 * (idx - 15) + 12; rf = fwF; }
            const bfu* qrow = qb + (size_t)(b * NQ + nq) * DIM + h * HD;
            float d = 0.f;
            for (int c = 0; c < HD; ++c)
                d += b2f(qrow[c]) * ldf(R, (size_t)ridx * HD + c, rf);
            if (idx < 8) bsT[rr][idx] = d; else bsD[rr][idx - 8] = d;
        }
    }
    __syncthreads();
    for (int id = t; id < 64 * 49; id += 256) {
        int rr = id / 49, r2 = id - rr * 49;
        bsHW[rr][r2] = bsD[rr][r2 / 7] + bsD[rr][7 + r2 % 7];
    }
    __syncthreads();

    int qw = rowbase + w * 16;           // wave's first q row (block-local base)
    if (qw >= NQ) return;                // whole-wave invalid; no barriers below

    size_t qgrow = (size_t)(b * NQ + qw + r) * DIM + h * HD;
    bf16x8 aq0 = *(const bf16x8*)(qb + qgrow + g * 8);
    bf16x8 aq1 = *(const bf16x8*)(qb + qgrow + 32 + g * 8);

    f32x4 o0, o1, o2, o3;
    #pragma unroll
    for (int i = 0; i < 4; ++i) { o0[i] = 0.f; o1[i] = 0.f; o2[i] = 0.f; o3[i] = 0.f; }
    float mr[4] = {-1e30f, -1e30f, -1e30f, -1e30f};
    float lr[4] = {0.f, 0.f, 0.f, 0.f};

    const bfu* kbase = kp + (size_t)bh * NKV * HD;
    const bfu* vbase = vt + (size_t)bh * HD * NKV;
    f32x4 zero;
    #pragma unroll
    for (int i = 0; i < 4; ++i) zero[i] = 0.f;

    for (int kt0 = 0; kt0 < NKV; kt0 += 32) {
        // ---- QK^T: 4 mfma ----
        f32x4 s0 = zero, s1 = zero;
        {
            const bfu* k0 = kbase + (size_t)(kt0 + r) * HD + g * 8;
            const bfu* k1 = kbase + (size_t)(kt0 + 16 + r) * HD + g * 8;
            bf16x8 kf;
            kf = *(const bf16x8*)(k0);
            s0 = __builtin_amdgcn_mfma_f32_16x16x32_bf16(aq0, kf, s0, 0, 0, 0);
            kf = *(const bf16x8*)(k0 + 32);
            s0 = __builtin_amdgcn_mfma_f32_16x16x32_bf16(aq1, kf, s0, 0, 0, 0);
            kf = *(const bf16x8*)(k1);
            s1 = __builtin_amdgcn_mfma_f32_16x16x32_bf16(aq0, kf, s1, 0, 0, 0);
            kf = *(const bf16x8*)(k1 + 32);
            s1 = __builtin_amdgcn_mfma_f32_16x16x32_bf16(aq1, kf, s1, 0, 0, 0);
        }
        // ---- scale + rel-pos bias + tail mask (BOTH halves; round-8 bug fix:
        // last tile kt0=384 has kj0=384+r >= 392 for r>=8 -> must mask s0 too)
        int kj0 = kt0 + r, kj1 = kt0 + 16 + r;
        bool msk0 = (kj0 >= NKV);
        bool msk1 = (kj1 >= NKV);
        int kj0c = msk0 ? (NKV - 1) : kj0;
        int kj1c = msk1 ? (NKV - 1) : kj1;
        int kt_0 = kj0c / 49, r2_0 = kj0c - kt_0 * 49;
        int kt_1 = kj1c / 49, r2_1 = kj1c - kt_1 * 49;
        #pragma unroll
        for (int i = 0; i < 4; ++i) {
            int br = w * 16 + 4 * g + i;
            float v0 = s0[i] * 0.125f + bsT[br][kt_0] + bsHW[br][r2_0];
            float v1 = s1[i] * 0.125f + bsT[br][kt_1] + bsHW[br][r2_1];
            s0[i] = msk0 ? -1e30f : v0;
            s1[i] = msk1 ? -1e30f : v1;
        }
        // ---- online softmax (rows live on 16 r-lanes within g-group) ----
        #pragma unroll
        for (int i = 0; i < 4; ++i) {
            float tm = fmaxf(s0[i], s1[i]);
            tm = fmaxf(tm, __shfl_xor(tm, 1));
            tm = fmaxf(tm, __shfl_xor(tm, 2));
            tm = fmaxf(tm, __shfl_xor(tm, 4));
            tm = fmaxf(tm, __shfl_xor(tm, 8));
            float mn = fmaxf(mr[i], tm);
            float sc = __expf(mr[i] - mn);
            float p0 = __expf(s0[i] - mn);
            float p1 = __expf(s1[i] - mn);
            p0 = b2f(f2b(p0));          // quantize so l matches PV's bf16 P
            p1 = b2f(f2b(p1));
            float rs = p0 + p1;
            rs += __shfl_xor(rs, 1);
            rs += __shfl_xor(rs, 2);
            rs += __shfl_xor(rs, 4);
            rs += __shfl_xor(rs, 8);
            lr[i] = lr[i] * sc + rs;
            mr[i] = mn;
            o0[i] *= sc; o1[i] *= sc; o2[i] *= sc; o3[i] *= sc;
            s0[i] = p0; s1[i] = p1;
        }
        // ---- P transpose through per-wave LDS tile ----
        #pragma unroll
        for (int i = 0; i < 4; ++i) {
            Pl[w][4 * g + i][r]      = f2b(s0[i]);
            Pl[w][4 * g + i][16 + r] = f2b(s1[i]);
        }
        bf16x8 pf = *(const bf16x8*)&Pl[w][r][8 * g];
        // ---- PV: 4 mfma, V^T rows are 16B-contiguous in kj ----
        const bfu* vb0 = vbase + (size_t)r * NKV + kt0 + 8 * g;
        bf16x8 vf;
        vf = *(const bf16x8*)(vb0);
        o0 = __builtin_amdgcn_mfma_f32_16x16x32_bf16(pf, vf, o0, 0, 0, 0);
        vf = *(const bf16x8*)(vb0 + 16 * NKV);
        o1 = __builtin_amdgcn_mfma_f32_16x16x32_bf16(pf, vf, o1, 0, 0, 0);
        vf = *(const bf16x8*)(vb0 + 32 * NKV);
        o2 = __builtin_amdgcn_mfma_f32_16x16x32_bf16(pf, vf, o2, 0, 0, 0);
        vf = *(const bf16x8*)(vb0 + 48 * NKV);
        o3 = __builtin_amdgcn_mfma_f32_16x16x32_bf16(pf, vf, o3, 0, 0, 0);
    }

    // ---- epilogue: normalize, +residual q, store ----
    #pragma unroll
    for (int i = 0; i < 4; ++i) {
        float inv = 1.f / lr[i];
        size_t orow = (size_t)(b * NQ + qw + 4 * g + i) * DIM + h * HD + r;
        ao[orow]      = f2b(o0[i] * inv + b2f(qb[orow]));
        ao[orow + 16] = f2b(o1[i] * inv + b2f(qb[orow + 16]));
        ao[orow + 32] = f2b(o2[i] * inv + b2f(qb[orow + 32]));
        ao[orow + 48] = f2b(o3[i] * inv + b2f(qb[orow + 48]));
    }
}

extern "C" void kernel_launch(void* const* d_in, const int* in_sizes, int n_in,
                              void* d_out, int out_size, void* d_ws, size_t ws_size,
                              hipStream_t stream) {
    Ptrs ptrs;
    for (int i = 0; i < 16; ++i) ptrs.p[i] = d_in[i];
    const void* x      = d_in[0];
    const void* ln_w   = d_in[1];
    const void* ln_b   = d_in[2];
    const void* qkv_w  = d_in[3];
    const void* qkv_b  = d_in[4];
    const void* proj_w = d_in[5];
    const void* proj_b = d_in[6];
    const void* poolk_w = d_in[7];
    const void* poolv_w = d_in[8];
    const void* rph    = d_in[13];
    const void* rpw    = d_in[14];
    const void* rpt    = d_in[15];

    bfu* ws = (bfu*)d_ws;
    bfu* A  = ws;                       // 4,816,896: xn, later attention out
    bfu* Bf = ws + 4816896;             // 4,816,896: k / v / q projections
    bfu* kp = ws + 9633792;             // 1,204,224: K  [bh][kj][d]
    bfu* vt = ws + 10838016;            // 1,204,224: V^T [bh][d][kj]
    int* flags = (int*)(ws + 12042240); // 64 bytes
    float* out = (float*)d_out;

    probe_kernel<<<16, 64, 0, stream>>>(ptrs, flags);

    ln_kernel<<<BATCH * NQ, 256, 0, stream>>>(x, ln_w, ln_b, A, flags);

    dim3 ggrid(49, 6);
    gemm_mfma_kernel<false><<<ggrid, 256, 0, stream>>>(A, qkv_w, qkv_b, Bf, DIM, 3 * DIM, flags, 3, 4);
    pool_ln_kernel<false><<<4704, 256, 0, stream>>>(Bf, poolk_w, d_in[9], d_in[10], kp, flags, 7, 9, 10);

    gemm_mfma_kernel<false><<<ggrid, 256, 0, stream>>>(A, qkv_w, qkv_b, Bf, 2 * DIM, 3 * DIM, flags, 3, 4);
    pool_ln_kernel<true><<<4704, 256, 0, stream>>>(Bf, poolv_w, d_in[11], d_in[12], vt, flags, 8, 11, 12);

    gemm_mfma_kernel<false><<<ggrid, 256, 0, stream>>>(A, qkv_w, qkv_b, Bf, 0, 3 * DIM, flags, 3, 4);

    attn_mfma_kernel<<<48 * 25, 256, 0, stream>>>(Bf, kp, vt, rpt, rph, rpw, A, flags);

    gemm_mfma_kernel<true><<<ggrid, 256, 0, stream>>>(A, proj_w, proj_b, out, 0, DIM, flags, 5, 6);
}

// Round 11
// 414.318 us; speedup vs baseline: 10.7637x; 1.6159x over previous
//
#include <hip/hip_runtime.h>
#include <math.h>

#define DIM 768
#define NHEADS 12
#define HD 64
#define BATCH 4
#define NQ 1568            // 8*14*14  (T,H,W = 8,14,14)
#define NKV 392            // 8*7*7
#define LN_EPS 1e-6f

typedef unsigned short bfu;
typedef __attribute__((ext_vector_type(8))) short bf16x8;
typedef __attribute__((ext_vector_type(4))) float f32x4;

__device__ __forceinline__ float b2f(bfu u) {
    union { unsigned int i; float f; } v; v.i = ((unsigned int)u) << 16; return v.f;
}
__device__ __forceinline__ bfu f2b(float f) {
    union { float f; unsigned int i; } v; v.f = f;
    unsigned int r = v.i + 0x7FFFu + ((v.i >> 16) & 1u);
    return (bfu)(r >> 16);
}
// runtime-dtype load: fl==1 -> f32, fl==0 -> bf16, fl==2 -> zeros tensor
__device__ __forceinline__ float ldf(const void* p, size_t i, int fl) {
    if (fl == 1) return ((const float*)p)[i];
    if (fl == 0) return b2f(((const bfu*)p)[i]);
    return 0.f;
}

struct Ptrs { const void* p[16]; };

// ---- per-tensor dtype probe (verified working) ----------------------------
__global__ __launch_bounds__(64) void probe_kernel(Ptrs ptrs, int* __restrict__ flags) {
    const int cnts[16] = {4816896, 768, 768, 1769472, 2304, 589824, 768,
                          1728, 1728, 64, 64, 64, 64, 1728, 1728, 960};
    int i = blockIdx.x;
    const bfu* u = (const bfu*)ptrs.p[i];
    int S = cnts[i]; if (S > 1024) S = 1024;
    int nz = 0, outb = 0;
    for (int j = threadIdx.x; j < S; j += 64) {
        bfu v = u[j];
        if (v != 0) nz++;
        if ((j & 1) == 0) {
            int e = (v >> 7) & 0xFF;
            if (e < 96 || e > 134) outb++;
        }
    }
    #pragma unroll
    for (int o = 1; o < 64; o <<= 1) { nz += __shfl_xor(nz, o); outb += __shfl_xor(outb, o); }
    if (threadIdx.x == 0) {
        int ne = (S + 1) >> 1;
        flags[i] = (nz == 0) ? 2 : ((2 * outb > ne) ? 1 : 0);
    }
}

// ---------------- LayerNorm over DIM=768, one row per block ----------------
__global__ __launch_bounds__(256) void ln_kernel(const void* __restrict__ x,
                                                 const void* __restrict__ w,
                                                 const void* __restrict__ b,
                                                 bfu* __restrict__ out,
                                                 const int* __restrict__ fl) {
    int fx = fl[0], fw = fl[1], fb = fl[2];
    int row = blockIdx.x;
    size_t base = (size_t)row * DIM;
    int t = threadIdx.x;
    float v0 = ldf(x, base + t, fx);
    float v1 = ldf(x, base + t + 256, fx);
    float v2 = ldf(x, base + t + 512, fx);
    float s = v0 + v1 + v2;
    float sq = v0 * v0 + v1 * v1 + v2 * v2;
    #pragma unroll
    for (int o = 1; o < 64; o <<= 1) { s += __shfl_xor(s, o); sq += __shfl_xor(sq, o); }
    __shared__ float ss[4], ssq[4];
    int wid = t >> 6;
    if ((t & 63) == 0) { ss[wid] = s; ssq[wid] = sq; }
    __syncthreads();
    s = ss[0] + ss[1] + ss[2] + ss[3];
    sq = ssq[0] + ssq[1] + ssq[2] + ssq[3];
    float mean = s * (1.0f / DIM);
    float var = sq * (1.0f / DIM) - mean * mean;
    float rs = rsqrtf(fmaxf(var, 0.0f) + LN_EPS);
    bfu* o = out + base;
    o[t]       = f2b((v0 - mean) * rs * ldf(w, t, fw)       + ldf(b, t, fb));
    o[t + 256] = f2b((v1 - mean) * rs * ldf(w, t + 256, fw) + ldf(b, t + 256, fb));
    o[t + 512] = f2b((v2 - mean) * rs * ldf(w, t + 512, fw) + ldf(b, t + 512, fb));
}

// ---- MFMA GEMM: C(6272 x 768) = A(bf16) @ W[:, woff:woff+768] + bias ------
// grid(49 row-tiles, 6 col-tiles): consecutive blocks share the W col-slab (L2)
template<bool F32OUT>
__global__ __launch_bounds__(256) void gemm_mfma_kernel(
    const bfu* __restrict__ A, const void* __restrict__ W,
    const void* __restrict__ bias, void* __restrict__ Cout,
    int woff, int wld, const int* __restrict__ fl, int fwi, int fbi) {
    int fw = fl[fwi], fb = fl[fbi];
    __shared__ bfu As[4096];              // 8 KB: [8 mgrp][4 kgrp][16 r][8 j]
    int t = threadIdx.x;
    int l = t & 63;
    int wv = t >> 6;
    int wr = wv >> 1, wc = wv & 1;
    int g = l >> 4, r = l & 15;
    int brow = blockIdx.x * 128;
    int bcol = blockIdx.y * 128;

    f32x4 acc[4][4];
    #pragma unroll
    for (int m = 0; m < 4; ++m)
        #pragma unroll
        for (int n = 0; n < 4; ++n)
            #pragma unroll
            for (int q = 0; q < 4; ++q) acc[m][n][q] = 0.f;

    int srow = t >> 1, sseg = t & 1;
    const bfu* agp = A + (size_t)(brow + srow) * DIM + sseg * 16;
    int w0 = (((srow >> 4) * 4 + sseg * 2 + 0) * 16 + (srow & 15)) * 8;
    int w1 = (((srow >> 4) * 4 + sseg * 2 + 1) * 16 + (srow & 15)) * 8;

    int gcol = bcol + wc * 64 + r;

    for (int k0 = 0; k0 < DIM; k0 += 32) {
        bf16x8 av0 = *(const bf16x8*)(agp + k0);
        bf16x8 av1 = *(const bf16x8*)(agp + k0 + 8);
        *(bf16x8*)&As[w0] = av0;
        *(bf16x8*)&As[w1] = av1;
        __syncthreads();

        bf16x8 bfrag[4];
        int krow = k0 + g * 8;
        #pragma unroll
        for (int n = 0; n < 4; ++n) {
            size_t cb = (size_t)krow * wld + woff + gcol + n * 16;
            #pragma unroll
            for (int j = 0; j < 8; ++j)
                bfrag[n][j] = (short)f2b(ldf(W, cb + (size_t)j * wld, fw));
        }
        bf16x8 afrag[4];
        #pragma unroll
        for (int m = 0; m < 4; ++m)
            afrag[m] = *(const bf16x8*)&As[(((wr * 4 + m) * 4 + g) * 16 + r) * 8];

        #pragma unroll
        for (int m = 0; m < 4; ++m)
            #pragma unroll
            for (int n = 0; n < 4; ++n)
                acc[m][n] = __builtin_amdgcn_mfma_f32_16x16x32_bf16(
                    afrag[m], bfrag[n], acc[m][n], 0, 0, 0);
        __syncthreads();
    }

    float bv[4];
    #pragma unroll
    for (int n = 0; n < 4; ++n) bv[n] = ldf(bias, woff + gcol + n * 16, fb);
    #pragma unroll
    for (int m = 0; m < 4; ++m) {
        #pragma unroll
        for (int n = 0; n < 4; ++n) {
            #pragma unroll
            for (int i = 0; i < 4; ++i) {
                float v = acc[m][n][i] + bv[n];
                size_t row = brow + wr * 64 + m * 16 + g * 4 + i;
                size_t col = bcol + wc * 64 + n * 16 + r;
                if (F32OUT) ((float*)Cout)[row * DIM + col] = v;
                else        ((bfu*)Cout)[row * DIM + col] = f2b(v);
            }
        }
    }
}

// ------------- depthwise conv3d pool (3x3x3, stride 1,2,2, pad 1) + LN -----
// TR=false: out[(bh*NKV + kpos)*64 + lane]   (K layout [bh][kj][d])
// TR=true : out[(bh*64 + lane)*NKV + kpos]   (V^T layout [bh][d][kj])
template<bool TR>
__global__ __launch_bounds__(256) void pool_ln_kernel(
    const bfu* __restrict__ kv, const void* __restrict__ pw,
    const void* __restrict__ lw, const void* __restrict__ lb,
    bfu* __restrict__ out, const int* __restrict__ fl,
    int fpi, int fwi, int fbi) {
    int fp = fl[fpi], fw = fl[fwi], fb = fl[fbi];
    int p = blockIdx.x * 4 + (threadIdx.x >> 6);
    int lane = threadIdx.x & 63;
    int b = p / (NHEADS * NKV);
    int rem = p % (NHEADS * NKV);
    int h = rem / NKV;
    int kpos = rem % NKV;
    int kt = kpos / 49;
    int r2 = kpos % 49;
    int kh = r2 / 7;
    int kw = r2 % 7;
    float acc = 0.f;
    #pragma unroll
    for (int dt = 0; dt < 3; ++dt) {
        int tt = kt + dt - 1;
        if (tt < 0 || tt >= 8) continue;
        #pragma unroll
        for (int dh = 0; dh < 3; ++dh) {
            int hh = kh * 2 + dh - 1;
            if (hh < 0 || hh >= 14) continue;
            #pragma unroll
            for (int dw = 0; dw < 3; ++dw) {
                int ww = kw * 2 + dw - 1;
                if (ww < 0 || ww >= 14) continue;
                int n = (tt * 14 + hh) * 14 + ww;
                float in = b2f(kv[(size_t)(b * NQ + n) * DIM + h * HD + lane]);
                acc += in * ldf(pw, lane * 27 + dt * 9 + dh * 3 + dw, fp);
            }
        }
    }
    float s = acc, sq = acc * acc;
    #pragma unroll
    for (int o = 1; o < 64; o <<= 1) { s += __shfl_xor(s, o); sq += __shfl_xor(sq, o); }
    float mean = s * (1.0f / 64.0f);
    float var = sq * (1.0f / 64.0f) - mean * mean;
    float rs = rsqrtf(fmaxf(var, 0.0f) + LN_EPS);
    float v = (acc - mean) * rs * ldf(lw, lane, fw) + ldf(lb, lane, fb);
    int bh = b * NHEADS + h;
    if (TR) out[((size_t)bh * HD + lane) * NKV + kpos] = f2b(v);
    else    out[((size_t)bh * NKV + kpos) * HD + lane] = f2b(v);
}

// ---- MFMA flash attention: block = 4 waves x 16 q-rows, kv tiles of 32 ----
// Bias phase: round-9 scalar arithmetic, but staged through LDS (Ql + Rl).
__global__ __launch_bounds__(256) void attn_mfma_kernel(
    const bfu* __restrict__ qb, const bfu* __restrict__ kp,
    const bfu* __restrict__ vt, const void* __restrict__ rpt,
    const void* __restrict__ rph, const void* __restrict__ rpw,
    bfu* __restrict__ ao, const int* __restrict__ fl) {
    int fh = fl[13], fwF = fl[14], ft = fl[15];
    // layout: Ql[64][64] f32 @0 (16384) | Rl[69][64] f32 @16384 (17664)
    //         bsT[64][8] f32 @34048 (2048) | bsD[64][14] f32 @36096 (3584)
    // overlays (after dots phase, Ql/Rl dead):
    //         bsHW[64][52] f32 @0 (13312) | Pl[4][16][40] bfu @13312 (5120)
    __shared__ __align__(16) unsigned char smem[39680];
    float (*Ql)[64]   = reinterpret_cast<float(*)[64]>(smem);
    float (*Rl)[64]   = reinterpret_cast<float(*)[64]>(smem + 16384);
    float (*bsT)[8]   = reinterpret_cast<float(*)[8]>(smem + 34048);
    float (*bsD)[14]  = reinterpret_cast<float(*)[14]>(smem + 36096);
    float (*bsHW)[52] = reinterpret_cast<float(*)[52]>(smem);
    bfu   (*Pl)[16][40] = reinterpret_cast<bfu(*)[16][40]>(smem + 13312);

    int t = threadIdx.x;
    int l = t & 63, w = t >> 6;
    int g = l >> 4, r = l & 15;
    int blk = blockIdx.x;
    int qt = blk % 25, bh = blk / 25;
    int h = bh % NHEADS, b = bh / NHEADS;
    int rowbase = qt * 64;
    int qw = rowbase + w * 16;

    // ---- phase 1: stage Q tile (bf16->f32) and R tables into LDS ----
    for (int id = t; id < 1024; id += 256) {           // 64 rows x 16 float4s
        int rr = id >> 4, c4 = (id & 15) << 2;
        int nq = rowbase + rr;
        float4 v;
        if (nq < NQ) {
            ushort4 u = *(const ushort4*)(qb + (size_t)(b * NQ + nq) * DIM + h * HD + c4);
            v = make_float4(b2f(u.x), b2f(u.y), b2f(u.z), b2f(u.w));
        } else {
            v = make_float4(0.f, 0.f, 0.f, 0.f);
        }
        *(float4*)&Ql[rr][c4] = v;
    }
    for (int id = t; id < 69 * 64; id += 256) {        // R_all = [rpt;rph;rpw]
        int j = id >> 6, c = id & 63;
        const void* R; int row, rfl;
        if (j < 15)      { R = rpt; row = j;      rfl = ft; }
        else if (j < 42) { R = rph; row = j - 15; rfl = fh; }
        else             { R = rpw; row = j - 42; rfl = fwF; }
        Rl[j][c] = ldf(R, (size_t)row * HD + c, rfl);
    }
    __syncthreads();

    // ---- phase 2: 22 rel-pos dots per q-row, all from LDS ----
    for (int id = t; id < 64 * 22; id += 256) {
        int rr = id / 22, idx = id - rr * 22;
        int nq = rowbase + rr;
        int tq = nq / 196, hq = (nq % 196) / 14, wq = nq % 14;
        int j;
        if (idx < 8)       j = tq - idx + 7;                  // rpt rows 0..14
        else if (idx < 15) j = 15 + hq - 2 * (idx - 8) + 12;  // rph rows 15..41
        else               j = 42 + wq - 2 * (idx - 15) + 12; // rpw rows 42..68
        float d = 0.f;
        #pragma unroll
        for (int c = 0; c < 64; c += 4) {
            float4 qv = *(const float4*)&Ql[rr][c];
            float4 rv = *(const float4*)&Rl[j][c];
            d += qv.x * rv.x; d += qv.y * rv.y; d += qv.z * rv.z; d += qv.w * rv.w;
        }
        if (idx < 8) bsT[rr][idx] = d; else bsD[rr][idx - 8] = d;
    }
    __syncthreads();

    // ---- phase 3: combine h+w biases (bsHW overlays dead Ql) ----
    for (int id = t; id < 64 * 49; id += 256) {
        int rr = id / 49, r2 = id - rr * 49;
        bsHW[rr][r2] = bsD[rr][r2 / 7] + bsD[rr][7 + r2 % 7];
    }
    __syncthreads();

    if (qw >= NQ) return;                // tail waves exit after all barriers

    size_t qgrow = (size_t)(b * NQ + qw + r) * DIM + h * HD;
    bf16x8 aq0 = *(const bf16x8*)(qb + qgrow + g * 8);
    bf16x8 aq1 = *(const bf16x8*)(qb + qgrow + 32 + g * 8);

    f32x4 o0, o1, o2, o3;
    #pragma unroll
    for (int i = 0; i < 4; ++i) { o0[i] = 0.f; o1[i] = 0.f; o2[i] = 0.f; o3[i] = 0.f; }
    float mr[4] = {-1e30f, -1e30f, -1e30f, -1e30f};
    float lr[4] = {0.f, 0.f, 0.f, 0.f};

    const bfu* kbase = kp + (size_t)bh * NKV * HD;
    const bfu* vbase = vt + (size_t)bh * HD * NKV;
    f32x4 zero;
    #pragma unroll
    for (int i = 0; i < 4; ++i) zero[i] = 0.f;

    for (int kt0 = 0; kt0 < NKV; kt0 += 32) {
        // ---- QK^T: 4 mfma ----
        f32x4 s0 = zero, s1 = zero;
        {
            const bfu* k0 = kbase + (size_t)(kt0 + r) * HD + g * 8;
            const bfu* k1 = kbase + (size_t)(kt0 + 16 + r) * HD + g * 8;
            bf16x8 kf;
            kf = *(const bf16x8*)(k0);
            s0 = __builtin_amdgcn_mfma_f32_16x16x32_bf16(aq0, kf, s0, 0, 0, 0);
            kf = *(const bf16x8*)(k0 + 32);
            s0 = __builtin_amdgcn_mfma_f32_16x16x32_bf16(aq1, kf, s0, 0, 0, 0);
            kf = *(const bf16x8*)(k1);
            s1 = __builtin_amdgcn_mfma_f32_16x16x32_bf16(aq0, kf, s1, 0, 0, 0);
            kf = *(const bf16x8*)(k1 + 32);
            s1 = __builtin_amdgcn_mfma_f32_16x16x32_bf16(aq1, kf, s1, 0, 0, 0);
        }
        // ---- scale + rel-pos bias + tail mask (both halves) ----
        int kj0 = kt0 + r, kj1 = kt0 + 16 + r;
        bool msk0 = (kj0 >= NKV);
        bool msk1 = (kj1 >= NKV);
        int kj0c = msk0 ? (NKV - 1) : kj0;
        int kj1c = msk1 ? (NKV - 1) : kj1;
        int kt_0 = kj0c / 49, r2_0 = kj0c - kt_0 * 49;
        int kt_1 = kj1c / 49, r2_1 = kj1c - kt_1 * 49;
        #pragma unroll
        for (int i = 0; i < 4; ++i) {
            int br = w * 16 + 4 * g + i;
            float v0 = s0[i] * 0.125f + bsT[br][kt_0] + bsHW[br][r2_0];
            float v1 = s1[i] * 0.125f + bsT[br][kt_1] + bsHW[br][r2_1];
            s0[i] = msk0 ? -1e30f : v0;
            s1[i] = msk1 ? -1e30f : v1;
        }
        // ---- online softmax (rows live on 16 r-lanes within g-group) ----
        #pragma unroll
        for (int i = 0; i < 4; ++i) {
            float tm = fmaxf(s0[i], s1[i]);
            tm = fmaxf(tm, __shfl_xor(tm, 1));
            tm = fmaxf(tm, __shfl_xor(tm, 2));
            tm = fmaxf(tm, __shfl_xor(tm, 4));
            tm = fmaxf(tm, __shfl_xor(tm, 8));
            float mn = fmaxf(mr[i], tm);
            float sc = __expf(mr[i] - mn);
            float p0 = __expf(s0[i] - mn);
            float p1 = __expf(s1[i] - mn);
            p0 = b2f(f2b(p0));          // quantize so l matches PV's bf16 P
            p1 = b2f(f2b(p1));
            float rs = p0 + p1;
            rs += __shfl_xor(rs, 1);
            rs += __shfl_xor(rs, 2);
            rs += __shfl_xor(rs, 4);
            rs += __shfl_xor(rs, 8);
            lr[i] = lr[i] * sc + rs;
            mr[i] = mn;
            o0[i] *= sc; o1[i] *= sc; o2[i] *= sc; o3[i] *= sc;
            s0[i] = p0; s1[i] = p1;
        }
        // ---- P transpose through per-wave LDS tile ----
        #pragma unroll
        for (int i = 0; i < 4; ++i) {
            Pl[w][4 * g + i][r]      = f2b(s0[i]);
            Pl[w][4 * g + i][16 + r] = f2b(s1[i]);
        }
        bf16x8 pf = *(const bf16x8*)&Pl[w][r][8 * g];
        // ---- PV: 4 mfma, V^T rows are 16B-contiguous in kj ----
        const bfu* vb0 = vbase + (size_t)r * NKV + kt0 + 8 * g;
        bf16x8 vf;
        vf = *(const bf16x8*)(vb0);
        o0 = __builtin_amdgcn_mfma_f32_16x16x32_bf16(pf, vf, o0, 0, 0, 0);
        vf = *(const bf16x8*)(vb0 + 16 * NKV);
        o1 = __builtin_amdgcn_mfma_f32_16x16x32_bf16(pf, vf, o1, 0, 0, 0);
        vf = *(const bf16x8*)(vb0 + 32 * NKV);
        o2 = __builtin_amdgcn_mfma_f32_16x16x32_bf16(pf, vf, o2, 0, 0, 0);
        vf = *(const bf16x8*)(vb0 + 48 * NKV);
        o3 = __builtin_amdgcn_mfma_f32_16x16x32_bf16(pf, vf, o3, 0, 0, 0);
    }

    // ---- epilogue: normalize, +residual q, store ----
    #pragma unroll
    for (int i = 0; i < 4; ++i) {
        float inv = 1.f / lr[i];
        size_t orow = (size_t)(b * NQ + qw + 4 * g + i) * DIM + h * HD + r;
        ao[orow]      = f2b(o0[i] * inv + b2f(qb[orow]));
        ao[orow + 16] = f2b(o1[i] * inv + b2f(qb[orow + 16]));
        ao[orow + 32] = f2b(o2[i] * inv + b2f(qb[orow + 32]));
        ao[orow + 48] = f2b(o3[i] * inv + b2f(qb[orow + 48]));
    }
}

extern "C" void kernel_launch(void* const* d_in, const int* in_sizes, int n_in,
                              void* d_out, int out_size, void* d_ws, size_t ws_size,
                              hipStream_t stream) {
    Ptrs ptrs;
    for (int i = 0; i < 16; ++i) ptrs.p[i] = d_in[i];
    const void* x      = d_in[0];
    const void* ln_w   = d_in[1];
    const void* ln_b   = d_in[2];
    const void* qkv_w  = d_in[3];
    const void* qkv_b  = d_in[4];
    const void* proj_w = d_in[5];
    const void* proj_b = d_in[6];
    const void* poolk_w = d_in[7];
    const void* poolv_w = d_in[8];
    const void* rph    = d_in[13];
    const void* rpw    = d_in[14];
    const void* rpt    = d_in[15];

    bfu* ws = (bfu*)d_ws;
    bfu* A  = ws;                       // 4,816,896: xn, later attention out
    bfu* Bf = ws + 4816896;             // 4,816,896: k / v / q projections
    bfu* kp = ws + 9633792;             // 1,204,224: K  [bh][kj][d]
    bfu* vt = ws + 10838016;            // 1,204,224: V^T [bh][d][kj]
    int* flags = (int*)(ws + 12042240); // 64 bytes
    float* out = (float*)d_out;

    probe_kernel<<<16, 64, 0, stream>>>(ptrs, flags);

    ln_kernel<<<BATCH * NQ, 256, 0, stream>>>(x, ln_w, ln_b, A, flags);

    dim3 ggrid(49, 6);
    gemm_mfma_kernel<false><<<ggrid, 256, 0, stream>>>(A, qkv_w, qkv_b, Bf, DIM, 3 * DIM, flags, 3, 4);
    pool_ln_kernel<false><<<4704, 256, 0, stream>>>(Bf, poolk_w, d_in[9], d_in[10], kp, flags, 7, 9, 10);

    gemm_mfma_kernel<false><<<ggrid, 256, 0, stream>>>(A, qkv_w, qkv_b, Bf, 2 * DIM, 3 * DIM, flags, 3, 4);
    pool_ln_kernel<true><<<4704, 256, 0, stream>>>(Bf, poolv_w, d_in[11], d_in[12], vt, flags, 8, 11, 12);

    gemm_mfma_kernel<false><<<ggrid, 256, 0, stream>>>(A, qkv_w, qkv_b, Bf, 0, 3 * DIM, flags, 3, 4);

    attn_mfma_kernel<<<48 * 25, 256, 0, stream>>>(Bf, kp, vt, rpt, rph, rpw, A, flags);

    gemm_mfma_kernel<true><<<ggrid, 256, 0, stream>>>(A, proj_w, proj_b, out, 0, DIM, flags, 5, 6);
}

// Round 12
// 318.746 us; speedup vs baseline: 13.9911x; 1.2998x over previous
//
#include <hip/hip_runtime.h>
#include <math.h>

#define DIM 768
#define NHEADS 12
#define HD 64
#define BATCH 4
#define NQ 1568            // 8*14*14  (T,H,W = 8,14,14)
#define NKV 392            // 8*7*7
#define LN_EPS 1e-6f

typedef unsigned short bfu;
typedef __attribute__((ext_vector_type(8))) short bf16x8;
typedef __attribute__((ext_vector_type(4))) float f32x4;

__device__ __forceinline__ float b2f(bfu u) {
    union { unsigned int i; float f; } v; v.i = ((unsigned int)u) << 16; return v.f;
}
__device__ __forceinline__ bfu f2b(float f) {
    union { float f; unsigned int i; } v; v.f = f;
    unsigned int r = v.i + 0x7FFFu + ((v.i >> 16) & 1u);
    return (bfu)(r >> 16);
}
// runtime-dtype load: fl==1 -> f32, fl==0 -> bf16, fl==2 -> zeros tensor
__device__ __forceinline__ float ldf(const void* p, size_t i, int fl) {
    if (fl == 1) return ((const float*)p)[i];
    if (fl == 0) return b2f(((const bfu*)p)[i]);
    return 0.f;
}

struct Ptrs { const void* p[16]; };

// ---- per-tensor dtype probe (verified working) ----------------------------
__global__ __launch_bounds__(64) void probe_kernel(Ptrs ptrs, int* __restrict__ flags) {
    const int cnts[16] = {4816896, 768, 768, 1769472, 2304, 589824, 768,
                          1728, 1728, 64, 64, 64, 64, 1728, 1728, 960};
    int i = blockIdx.x;
    const bfu* u = (const bfu*)ptrs.p[i];
    int S = cnts[i]; if (S > 1024) S = 1024;
    int nz = 0, outb = 0;
    for (int j = threadIdx.x; j < S; j += 64) {
        bfu v = u[j];
        if (v != 0) nz++;
        if ((j & 1) == 0) {
            int e = (v >> 7) & 0xFF;
            if (e < 96 || e > 134) outb++;
        }
    }
    #pragma unroll
    for (int o = 1; o < 64; o <<= 1) { nz += __shfl_xor(nz, o); outb += __shfl_xor(outb, o); }
    if (threadIdx.x == 0) {
        int ne = (S + 1) >> 1;
        flags[i] = (nz == 0) ? 2 : ((2 * outb > ne) ? 1 : 0);
    }
}

// ---------------- LayerNorm over DIM=768, one row per block ----------------
__global__ __launch_bounds__(256) void ln_kernel(const void* __restrict__ x,
                                                 const void* __restrict__ w,
                                                 const void* __restrict__ b,
                                                 bfu* __restrict__ out,
                                                 const int* __restrict__ fl) {
    int fx = fl[0], fw = fl[1], fb = fl[2];
    int row = blockIdx.x;
    size_t base = (size_t)row * DIM;
    int t = threadIdx.x;
    float v0 = ldf(x, base + t, fx);
    float v1 = ldf(x, base + t + 256, fx);
    float v2 = ldf(x, base + t + 512, fx);
    float s = v0 + v1 + v2;
    float sq = v0 * v0 + v1 * v1 + v2 * v2;
    #pragma unroll
    for (int o = 1; o < 64; o <<= 1) { s += __shfl_xor(s, o); sq += __shfl_xor(sq, o); }
    __shared__ float ss[4], ssq[4];
    int wid = t >> 6;
    if ((t & 63) == 0) { ss[wid] = s; ssq[wid] = sq; }
    __syncthreads();
    s = ss[0] + ss[1] + ss[2] + ss[3];
    sq = ssq[0] + ssq[1] + ssq[2] + ssq[3];
    float mean = s * (1.0f / DIM);
    float var = sq * (1.0f / DIM) - mean * mean;
    float rs = rsqrtf(fmaxf(var, 0.0f) + LN_EPS);
    bfu* o = out + base;
    o[t]       = f2b((v0 - mean) * rs * ldf(w, t, fw)       + ldf(b, t, fb));
    o[t + 256] = f2b((v1 - mean) * rs * ldf(w, t + 256, fw) + ldf(b, t + 256, fb));
    o[t + 512] = f2b((v2 - mean) * rs * ldf(w, t + 512, fw) + ldf(b, t + 512, fb));
}

// ---- weight transform: WT[col][k] = bf16(W[k][col]), K=768 ----------------
// 64x64 tile via LDS (pad 66: conflict-free transpose)
__global__ __launch_bounds__(256) void wcvt_kernel(
    const void* __restrict__ W, bfu* __restrict__ WT,
    int ncols, const int* __restrict__ fl, int fwi) {
    int fw = fl[fwi];
    __shared__ bfu tile[64][66];
    int c0 = blockIdx.x * 64;
    int k0 = blockIdx.y * 64;
    int t = threadIdx.x;
    for (int id = t; id < 4096; id += 256) {
        int kk = id >> 6, cc = id & 63;
        tile[cc][kk] = f2b(ldf(W, (size_t)(k0 + kk) * ncols + c0 + cc, fw));
    }
    __syncthreads();
    for (int id = t; id < 4096; id += 256) {
        int cc = id >> 6, kk = id & 63;
        WT[(size_t)(c0 + cc) * 768 + k0 + kk] = tile[cc][kk];
    }
}

// ---- MFMA GEMM: C(6272 x 768) = A(bf16) @ WT^T + bias --------------------
// WT is bf16 [col][k] (k contiguous): B-fragment = one 16B load.
template<bool F32OUT>
__global__ __launch_bounds__(256) void gemm_mfma_kernel(
    const bfu* __restrict__ A, const bfu* __restrict__ WT,
    const void* __restrict__ bias, void* __restrict__ Cout,
    int woff, const int* __restrict__ fl, int fbi) {
    int fb = fl[fbi];
    __shared__ bfu As[4096];              // 8 KB: [8 mgrp][4 kgrp][16 r][8 j]
    int t = threadIdx.x;
    int l = t & 63;
    int wv = t >> 6;
    int wr = wv >> 1, wc = wv & 1;
    int g = l >> 4, r = l & 15;
    int brow = blockIdx.x * 128;
    int bcol = blockIdx.y * 128;

    f32x4 acc[4][4];
    #pragma unroll
    for (int m = 0; m < 4; ++m)
        #pragma unroll
        for (int n = 0; n < 4; ++n)
            #pragma unroll
            for (int q = 0; q < 4; ++q) acc[m][n][q] = 0.f;

    int srow = t >> 1, sseg = t & 1;
    const bfu* agp = A + (size_t)(brow + srow) * DIM + sseg * 16;
    int w0 = (((srow >> 4) * 4 + sseg * 2 + 0) * 16 + (srow & 15)) * 8;
    int w1 = (((srow >> 4) * 4 + sseg * 2 + 1) * 16 + (srow & 15)) * 8;

    int gcol = bcol + wc * 64 + r;

    for (int k0 = 0; k0 < DIM; k0 += 32) {
        bf16x8 av0 = *(const bf16x8*)(agp + k0);
        bf16x8 av1 = *(const bf16x8*)(agp + k0 + 8);
        *(bf16x8*)&As[w0] = av0;
        *(bf16x8*)&As[w1] = av1;
        __syncthreads();

        int krow = k0 + g * 8;
        bf16x8 bfrag[4];
        #pragma unroll
        for (int n = 0; n < 4; ++n)
            bfrag[n] = *(const bf16x8*)(WT + (size_t)(gcol + n * 16) * 768 + krow);

        bf16x8 afrag[4];
        #pragma unroll
        for (int m = 0; m < 4; ++m)
            afrag[m] = *(const bf16x8*)&As[(((wr * 4 + m) * 4 + g) * 16 + r) * 8];

        #pragma unroll
        for (int m = 0; m < 4; ++m)
            #pragma unroll
            for (int n = 0; n < 4; ++n)
                acc[m][n] = __builtin_amdgcn_mfma_f32_16x16x32_bf16(
                    afrag[m], bfrag[n], acc[m][n], 0, 0, 0);
        __syncthreads();
    }

    float bv[4];
    #pragma unroll
    for (int n = 0; n < 4; ++n) bv[n] = ldf(bias, woff + gcol + n * 16, fb);
    #pragma unroll
    for (int m = 0; m < 4; ++m) {
        #pragma unroll
        for (int n = 0; n < 4; ++n) {
            #pragma unroll
            for (int i = 0; i < 4; ++i) {
                float v = acc[m][n][i] + bv[n];
                size_t row = brow + wr * 64 + m * 16 + g * 4 + i;
                size_t col = bcol + wc * 64 + n * 16 + r;
                if (F32OUT) ((float*)Cout)[row * DIM + col] = v;
                else        ((bfu*)Cout)[row * DIM + col] = f2b(v);
            }
        }
    }
}

// ------------- depthwise conv3d pool (3x3x3, stride 1,2,2, pad 1) + LN -----
// TR=false: out[(bh*NKV + kpos)*64 + lane]   (K layout [bh][kj][d])
// TR=true : out[(bh*64 + lane)*NKV + kpos]   (V^T layout [bh][d][kj])
template<bool TR>
__global__ __launch_bounds__(256) void pool_ln_kernel(
    const bfu* __restrict__ kv, const void* __restrict__ pw,
    const void* __restrict__ lw, const void* __restrict__ lb,
    bfu* __restrict__ out, const int* __restrict__ fl,
    int fpi, int fwi, int fbi) {
    int fp = fl[fpi], fw = fl[fwi], fb = fl[fbi];
    int p = blockIdx.x * 4 + (threadIdx.x >> 6);
    int lane = threadIdx.x & 63;
    int b = p / (NHEADS * NKV);
    int rem = p % (NHEADS * NKV);
    int h = rem / NKV;
    int kpos = rem % NKV;
    int kt = kpos / 49;
    int r2 = kpos % 49;
    int kh = r2 / 7;
    int kw = r2 % 7;
    float acc = 0.f;
    #pragma unroll
    for (int dt = 0; dt < 3; ++dt) {
        int tt = kt + dt - 1;
        if (tt < 0 || tt >= 8) continue;
        #pragma unroll
        for (int dh = 0; dh < 3; ++dh) {
            int hh = kh * 2 + dh - 1;
            if (hh < 0 || hh >= 14) continue;
            #pragma unroll
            for (int dw = 0; dw < 3; ++dw) {
                int ww = kw * 2 + dw - 1;
                if (ww < 0 || ww >= 14) continue;
                int n = (tt * 14 + hh) * 14 + ww;
                float in = b2f(kv[(size_t)(b * NQ + n) * DIM + h * HD + lane]);
                acc += in * ldf(pw, lane * 27 + dt * 9 + dh * 3 + dw, fp);
            }
        }
    }
    float s = acc, sq = acc * acc;
    #pragma unroll
    for (int o = 1; o < 64; o <<= 1) { s += __shfl_xor(s, o); sq += __shfl_xor(sq, o); }
    float mean = s * (1.0f / 64.0f);
    float var = sq * (1.0f / 64.0f) - mean * mean;
    float rs = rsqrtf(fmaxf(var, 0.0f) + LN_EPS);
    float v = (acc - mean) * rs * ldf(lw, lane, fw) + ldf(lb, lane, fb);
    int bh = b * NHEADS + h;
    if (TR) out[((size_t)bh * HD + lane) * NKV + kpos] = f2b(v);
    else    out[((size_t)bh * NKV + kpos) * HD + lane] = f2b(v);
}

// ---- MFMA flash attention: block = 4 waves x 16 q-rows, kv tiles of 32 ----
// Bias phase: round-11 arithmetic; Ql/Rl padded to stride 68 (bank spread).
__global__ __launch_bounds__(256) void attn_mfma_kernel(
    const bfu* __restrict__ qb, const bfu* __restrict__ kp,
    const bfu* __restrict__ vt, const void* __restrict__ rpt,
    const void* __restrict__ rph, const void* __restrict__ rpw,
    bfu* __restrict__ ao, const int* __restrict__ fl) {
    int fh = fl[13], fwF = fl[14], ft = fl[15];
    // layout: Ql[64][68] f32 @0 (17408) | Rl[69][68] f32 @17408 (18768)
    //         bsT[64][8] f32 @36176 (2048) | bsD[64][14] f32 @38224 (3584)
    // overlays (after dots phase, Ql/Rl dead):
    //         bsHW[64][52] f32 @0 (13312) | Pl[4][16][40] bfu @13312 (5120)
    __shared__ __align__(16) unsigned char smem[41808];
    float (*Ql)[68]   = reinterpret_cast<float(*)[68]>(smem);
    float (*Rl)[68]   = reinterpret_cast<float(*)[68]>(smem + 17408);
    float (*bsT)[8]   = reinterpret_cast<float(*)[8]>(smem + 36176);
    float (*bsD)[14]  = reinterpret_cast<float(*)[14]>(smem + 38224);
    float (*bsHW)[52] = reinterpret_cast<float(*)[52]>(smem);
    bfu   (*Pl)[16][40] = reinterpret_cast<bfu(*)[16][40]>(smem + 13312);

    int t = threadIdx.x;
    int l = t & 63, w = t >> 6;
    int g = l >> 4, r = l & 15;
    int blk = blockIdx.x;
    int qt = blk % 25, bh = blk / 25;
    int h = bh % NHEADS, b = bh / NHEADS;
    int rowbase = qt * 64;
    int qw = rowbase + w * 16;

    // ---- phase 1: stage Q tile (bf16->f32) and R tables into LDS ----
    for (int id = t; id < 1024; id += 256) {           // 64 rows x 16 float4s
        int rr = id >> 4, c4 = (id & 15) << 2;
        int nq = rowbase + rr;
        float4 v;
        if (nq < NQ) {
            ushort4 u = *(const ushort4*)(qb + (size_t)(b * NQ + nq) * DIM + h * HD + c4);
            v = make_float4(b2f(u.x), b2f(u.y), b2f(u.z), b2f(u.w));
        } else {
            v = make_float4(0.f, 0.f, 0.f, 0.f);
        }
        *(float4*)&Ql[rr][c4] = v;
    }
    for (int id = t; id < 69 * 64; id += 256) {        // R_all = [rpt;rph;rpw]
        int j = id >> 6, c = id & 63;
        const void* R; int row, rfl;
        if (j < 15)      { R = rpt; row = j;      rfl = ft; }
        else if (j < 42) { R = rph; row = j - 15; rfl = fh; }
        else             { R = rpw; row = j - 42; rfl = fwF; }
        Rl[j][c] = ldf(R, (size_t)row * HD + c, rfl);
    }
    __syncthreads();

    // ---- phase 2: 22 rel-pos dots per q-row, all from LDS ----
    for (int id = t; id < 64 * 22; id += 256) {
        int rr = id / 22, idx = id - rr * 22;
        int nq = rowbase + rr;
        int tq = nq / 196, hq = (nq % 196) / 14, wq = nq % 14;
        int j;
        if (idx < 8)       j = tq - idx + 7;                  // rpt rows 0..14
        else if (idx < 15) j = 15 + hq - 2 * (idx - 8) + 12;  // rph rows 15..41
        else               j = 42 + wq - 2 * (idx - 15) + 12; // rpw rows 42..68
        float d = 0.f;
        #pragma unroll
        for (int c = 0; c < 64; c += 4) {
            float4 qv = *(const float4*)&Ql[rr][c];
            float4 rv = *(const float4*)&Rl[j][c];
            d += qv.x * rv.x; d += qv.y * rv.y; d += qv.z * rv.z; d += qv.w * rv.w;
        }
        if (idx < 8) bsT[rr][idx] = d; else bsD[rr][idx - 8] = d;
    }
    __syncthreads();

    // ---- phase 3: combine h+w biases (bsHW overlays dead Ql) ----
    for (int id = t; id < 64 * 49; id += 256) {
        int rr = id / 49, r2 = id - rr * 49;
        bsHW[rr][r2] = bsD[rr][r2 / 7] + bsD[rr][7 + r2 % 7];
    }
    __syncthreads();

    if (qw >= NQ) return;                // tail waves exit after all barriers

    size_t qgrow = (size_t)(b * NQ + qw + r) * DIM + h * HD;
    bf16x8 aq0 = *(const bf16x8*)(qb + qgrow + g * 8);
    bf16x8 aq1 = *(const bf16x8*)(qb + qgrow + 32 + g * 8);

    f32x4 o0, o1, o2, o3;
    #pragma unroll
    for (int i = 0; i < 4; ++i) { o0[i] = 0.f; o1[i] = 0.f; o2[i] = 0.f; o3[i] = 0.f; }
    float mr[4] = {-1e30f, -1e30f, -1e30f, -1e30f};
    float lr[4] = {0.f, 0.f, 0.f, 0.f};

    const bfu* kbase = kp + (size_t)bh * NKV * HD;
    const bfu* vbase = vt + (size_t)bh * HD * NKV;
    f32x4 zero;
    #pragma unroll
    for (int i = 0; i < 4; ++i) zero[i] = 0.f;

    for (int kt0 = 0; kt0 < NKV; kt0 += 32) {
        // ---- QK^T: 4 mfma ----
        f32x4 s0 = zero, s1 = zero;
        {
            const bfu* k0 = kbase + (size_t)(kt0 + r) * HD + g * 8;
            const bfu* k1 = kbase + (size_t)(kt0 + 16 + r) * HD + g * 8;
            bf16x8 kf;
            kf = *(const bf16x8*)(k0);
            s0 = __builtin_amdgcn_mfma_f32_16x16x32_bf16(aq0, kf, s0, 0, 0, 0);
            kf = *(const bf16x8*)(k0 + 32);
            s0 = __builtin_amdgcn_mfma_f32_16x16x32_bf16(aq1, kf, s0, 0, 0, 0);
            kf = *(const bf16x8*)(k1);
            s1 = __builtin_amdgcn_mfma_f32_16x16x32_bf16(aq0, kf, s1, 0, 0, 0);
            kf = *(const bf16x8*)(k1 + 32);
            s1 = __builtin_amdgcn_mfma_f32_16x16x32_bf16(aq1, kf, s1, 0, 0, 0);
        }
        // ---- scale + rel-pos bias + tail mask (both halves) ----
        int kj0 = kt0 + r, kj1 = kt0 + 16 + r;
        bool msk0 = (kj0 >= NKV);
        bool msk1 = (kj1 >= NKV);
        int kj0c = msk0 ? (NKV - 1) : kj0;
        int kj1c = msk1 ? (NKV - 1) : kj1;
        int kt_0 = kj0c / 49, r2_0 = kj0c - kt_0 * 49;
        int kt_1 = kj1c / 49, r2_1 = kj1c - kt_1 * 49;
        #pragma unroll
        for (int i = 0; i < 4; ++i) {
            int br = w * 16 + 4 * g + i;
            float v0 = s0[i] * 0.125f + bsT[br][kt_0] + bsHW[br][r2_0];
            float v1 = s1[i] * 0.125f + bsT[br][kt_1] + bsHW[br][r2_1];
            s0[i] = msk0 ? -1e30f : v0;
            s1[i] = msk1 ? -1e30f : v1;
        }
        // ---- online softmax (rows live on 16 r-lanes within g-group) ----
        #pragma unroll
        for (int i = 0; i < 4; ++i) {
            float tm = fmaxf(s0[i], s1[i]);
            tm = fmaxf(tm, __shfl_xor(tm, 1));
            tm = fmaxf(tm, __shfl_xor(tm, 2));
            tm = fmaxf(tm, __shfl_xor(tm, 4));
            tm = fmaxf(tm, __shfl_xor(tm, 8));
            float mn = fmaxf(mr[i], tm);
            float sc = __expf(mr[i] - mn);
            float p0 = __expf(s0[i] - mn);
            float p1 = __expf(s1[i] - mn);
            p0 = b2f(f2b(p0));          // quantize so l matches PV's bf16 P
            p1 = b2f(f2b(p1));
            float rs = p0 + p1;
            rs += __shfl_xor(rs, 1);
            rs += __shfl_xor(rs, 2);
            rs += __shfl_xor(rs, 4);
            rs += __shfl_xor(rs, 8);
            lr[i] = lr[i] * sc + rs;
            mr[i] = mn;
            o0[i] *= sc; o1[i] *= sc; o2[i] *= sc; o3[i] *= sc;
            s0[i] = p0; s1[i] = p1;
        }
        // ---- P transpose through per-wave LDS tile ----
        #pragma unroll
        for (int i = 0; i < 4; ++i) {
            Pl[w][4 * g + i][r]      = f2b(s0[i]);
            Pl[w][4 * g + i][16 + r] = f2b(s1[i]);
        }
        bf16x8 pf = *(const bf16x8*)&Pl[w][r][8 * g];
        // ---- PV: 4 mfma, V^T rows are 16B-contiguous in kj ----
        const bfu* vb0 = vbase + (size_t)r * NKV + kt0 + 8 * g;
        bf16x8 vf;
        vf = *(const bf16x8*)(vb0);
        o0 = __builtin_amdgcn_mfma_f32_16x16x32_bf16(pf, vf, o0, 0, 0, 0);
        vf = *(const bf16x8*)(vb0 + 16 * NKV);
        o1 = __builtin_amdgcn_mfma_f32_16x16x32_bf16(pf, vf, o1, 0, 0, 0);
        vf = *(const bf16x8*)(vb0 + 32 * NKV);
        o2 = __builtin_amdgcn_mfma_f32_16x16x32_bf16(pf, vf, o2, 0, 0, 0);
        vf = *(const bf16x8*)(vb0 + 48 * NKV);
        o3 = __builtin_amdgcn_mfma_f32_16x16x32_bf16(pf, vf, o3, 0, 0, 0);
    }

    // ---- epilogue: normalize, +residual q, store ----
    #pragma unroll
    for (int i = 0; i < 4; ++i) {
        float inv = 1.f / lr[i];
        size_t orow = (size_t)(b * NQ + qw + 4 * g + i) * DIM + h * HD + r;
        ao[orow]      = f2b(o0[i] * inv + b2f(qb[orow]));
        ao[orow + 16] = f2b(o1[i] * inv + b2f(qb[orow + 16]));
        ao[orow + 32] = f2b(o2[i] * inv + b2f(qb[orow + 32]));
        ao[orow + 48] = f2b(o3[i] * inv + b2f(qb[orow + 48]));
    }
}

extern "C" void kernel_launch(void* const* d_in, const int* in_sizes, int n_in,
                              void* d_out, int out_size, void* d_ws, size_t ws_size,
                              hipStream_t stream) {
    Ptrs ptrs;
    for (int i = 0; i < 16; ++i) ptrs.p[i] = d_in[i];
    const void* x      = d_in[0];
    const void* ln_w   = d_in[1];
    const void* ln_b   = d_in[2];
    const void* qkv_w  = d_in[3];
    const void* qkv_b  = d_in[4];
    const void* proj_w = d_in[5];
    const void* proj_b = d_in[6];
    const void* poolk_w = d_in[7];
    const void* poolv_w = d_in[8];
    const void* rph    = d_in[13];
    const void* rpw    = d_in[14];
    const void* rpt    = d_in[15];

    bfu* ws = (bfu*)d_ws;
    bfu* A  = ws;                       // 4,816,896: xn, later attention out
    bfu* Bf = ws + 4816896;             // 4,816,896: k / v / q projections
    bfu* kp = ws + 9633792;             // 1,204,224: K [bh][kj][d]; later WT_proj
    bfu* vt = ws + 10838016;            // 1,204,224: V^T [bh][d][kj]
    int* flags = (int*)(ws + 12042240); // 64 bytes
    float* out = (float*)d_out;
    bfu* WTq = (bfu*)d_out;             // 2304x768 bf16 W^T, dead before proj GEMM

    probe_kernel<<<16, 64, 0, stream>>>(ptrs, flags);

    ln_kernel<<<BATCH * NQ, 256, 0, stream>>>(x, ln_w, ln_b, A, flags);

    // qkv_w (f32 [768][2304]) -> bf16 W^T [2304][768] in d_out scratch
    wcvt_kernel<<<dim3(36, 12), 256, 0, stream>>>(qkv_w, WTq, 3 * DIM, flags, 3);

    dim3 ggrid(49, 6);
    // k slice (cols 768..1535)
    gemm_mfma_kernel<false><<<ggrid, 256, 0, stream>>>(A, WTq + (size_t)DIM * 768, qkv_b, Bf, DIM, flags, 4);
    pool_ln_kernel<false><<<4704, 256, 0, stream>>>(Bf, poolk_w, d_in[9], d_in[10], kp, flags, 7, 9, 10);

    // v slice (cols 1536..2303)
    gemm_mfma_kernel<false><<<ggrid, 256, 0, stream>>>(A, WTq + (size_t)(2 * DIM) * 768, qkv_b, Bf, 2 * DIM, flags, 4);
    pool_ln_kernel<true><<<4704, 256, 0, stream>>>(Bf, poolv_w, d_in[11], d_in[12], vt, flags, 8, 11, 12);

    // q slice (cols 0..767)
    gemm_mfma_kernel<false><<<ggrid, 256, 0, stream>>>(A, WTq, qkv_b, Bf, 0, flags, 4);

    attn_mfma_kernel<<<48 * 25, 256, 0, stream>>>(Bf, kp, vt, rpt, rph, rpw, A, flags);

    // proj_w -> bf16 W^T into kp region (kp dead after attn)
    wcvt_kernel<<<dim3(12, 12), 256, 0, stream>>>(proj_w, kp, DIM, flags, 5);

    gemm_mfma_kernel<true><<<ggrid, 256, 0, stream>>>(A, kp, proj_b, out, 0, flags, 6);
}

// Round 13
// 312.476 us; speedup vs baseline: 14.2718x; 1.0201x over previous
//
#include <hip/hip_runtime.h>
#include <math.h>

#define DIM 768
#define NHEADS 12
#define HD 64
#define BATCH 4
#define NQ 1568            // 8*14*14  (T,H,W = 8,14,14)
#define NKV 392            // 8*7*7
#define LN_EPS 1e-6f

typedef unsigned short bfu;
typedef __attribute__((ext_vector_type(8))) short bf16x8;
typedef __attribute__((ext_vector_type(4))) float f32x4;

__device__ __forceinline__ float b2f(bfu u) {
    union { unsigned int i; float f; } v; v.i = ((unsigned int)u) << 16; return v.f;
}
__device__ __forceinline__ bfu f2b(float f) {
    union { float f; unsigned int i; } v; v.f = f;
    unsigned int r = v.i + 0x7FFFu + ((v.i >> 16) & 1u);
    return (bfu)(r >> 16);
}
// runtime-dtype load: fl==1 -> f32, fl==0 -> bf16, fl==2 -> zeros tensor
__device__ __forceinline__ float ldf(const void* p, size_t i, int fl) {
    if (fl == 1) return ((const float*)p)[i];
    if (fl == 0) return b2f(((const bfu*)p)[i]);
    return 0.f;
}

struct Ptrs { const void* p[16]; };

// ---- per-tensor dtype probe (verified working) ----------------------------
__global__ __launch_bounds__(64) void probe_kernel(Ptrs ptrs, int* __restrict__ flags) {
    const int cnts[16] = {4816896, 768, 768, 1769472, 2304, 589824, 768,
                          1728, 1728, 64, 64, 64, 64, 1728, 1728, 960};
    int i = blockIdx.x;
    const bfu* u = (const bfu*)ptrs.p[i];
    int S = cnts[i]; if (S > 1024) S = 1024;
    int nz = 0, outb = 0;
    for (int j = threadIdx.x; j < S; j += 64) {
        bfu v = u[j];
        if (v != 0) nz++;
        if ((j & 1) == 0) {
            int e = (v >> 7) & 0xFF;
            if (e < 96 || e > 134) outb++;
        }
    }
    #pragma unroll
    for (int o = 1; o < 64; o <<= 1) { nz += __shfl_xor(nz, o); outb += __shfl_xor(outb, o); }
    if (threadIdx.x == 0) {
        int ne = (S + 1) >> 1;
        flags[i] = (nz == 0) ? 2 : ((2 * outb > ne) ? 1 : 0);
    }
}

// ---------------- LayerNorm over DIM=768, one row per block ----------------
__global__ __launch_bounds__(256) void ln_kernel(const void* __restrict__ x,
                                                 const void* __restrict__ w,
                                                 const void* __restrict__ b,
                                                 bfu* __restrict__ out,
                                                 const int* __restrict__ fl) {
    int fx = fl[0], fw = fl[1], fb = fl[2];
    int row = blockIdx.x;
    size_t base = (size_t)row * DIM;
    int t = threadIdx.x;
    float v0 = ldf(x, base + t, fx);
    float v1 = ldf(x, base + t + 256, fx);
    float v2 = ldf(x, base + t + 512, fx);
    float s = v0 + v1 + v2;
    float sq = v0 * v0 + v1 * v1 + v2 * v2;
    #pragma unroll
    for (int o = 1; o < 64; o <<= 1) { s += __shfl_xor(s, o); sq += __shfl_xor(sq, o); }
    __shared__ float ss[4], ssq[4];
    int wid = t >> 6;
    if ((t & 63) == 0) { ss[wid] = s; ssq[wid] = sq; }
    __syncthreads();
    s = ss[0] + ss[1] + ss[2] + ss[3];
    sq = ssq[0] + ssq[1] + ssq[2] + ssq[3];
    float mean = s * (1.0f / DIM);
    float var = sq * (1.0f / DIM) - mean * mean;
    float rs = rsqrtf(fmaxf(var, 0.0f) + LN_EPS);
    bfu* o = out + base;
    o[t]       = f2b((v0 - mean) * rs * ldf(w, t, fw)       + ldf(b, t, fb));
    o[t + 256] = f2b((v1 - mean) * rs * ldf(w, t + 256, fw) + ldf(b, t + 256, fb));
    o[t + 512] = f2b((v2 - mean) * rs * ldf(w, t + 512, fw) + ldf(b, t + 512, fb));
}

// ---- weight transform: WT[col][k] = bf16(W[k][col]), K=768 ----------------
// 64x64 tile via LDS (pad 66: conflict-free transpose)
__global__ __launch_bounds__(256) void wcvt_kernel(
    const void* __restrict__ W, bfu* __restrict__ WT,
    int ncols, const int* __restrict__ fl, int fwi) {
    int fw = fl[fwi];
    __shared__ bfu tile[64][66];
    int c0 = blockIdx.x * 64;
    int k0 = blockIdx.y * 64;
    int t = threadIdx.x;
    for (int id = t; id < 4096; id += 256) {
        int kk = id >> 6, cc = id & 63;
        tile[cc][kk] = f2b(ldf(W, (size_t)(k0 + kk) * ncols + c0 + cc, fw));
    }
    __syncthreads();
    for (int id = t; id < 4096; id += 256) {
        int cc = id >> 6, kk = id & 63;
        WT[(size_t)(c0 + cc) * 768 + k0 + kk] = tile[cc][kk];
    }
}

// ---- MFMA GEMM: C(6272 x 768) = A(bf16) @ WT^T + bias --------------------
// WT is bf16 [col][k] (k contiguous): B-fragment = one 16B load.
template<bool F32OUT>
__global__ __launch_bounds__(256) void gemm_mfma_kernel(
    const bfu* __restrict__ A, const bfu* __restrict__ WT,
    const void* __restrict__ bias, void* __restrict__ Cout,
    int woff, const int* __restrict__ fl, int fbi) {
    int fb = fl[fbi];
    __shared__ bfu As[4096];              // 8 KB: [8 mgrp][4 kgrp][16 r][8 j]
    int t = threadIdx.x;
    int l = t & 63;
    int wv = t >> 6;
    int wr = wv >> 1, wc = wv & 1;
    int g = l >> 4, r = l & 15;
    int brow = blockIdx.x * 128;
    int bcol = blockIdx.y * 128;

    f32x4 acc[4][4];
    #pragma unroll
    for (int m = 0; m < 4; ++m)
        #pragma unroll
        for (int n = 0; n < 4; ++n)
            #pragma unroll
            for (int q = 0; q < 4; ++q) acc[m][n][q] = 0.f;

    int srow = t >> 1, sseg = t & 1;
    const bfu* agp = A + (size_t)(brow + srow) * DIM + sseg * 16;
    int w0 = (((srow >> 4) * 4 + sseg * 2 + 0) * 16 + (srow & 15)) * 8;
    int w1 = (((srow >> 4) * 4 + sseg * 2 + 1) * 16 + (srow & 15)) * 8;

    int gcol = bcol + wc * 64 + r;

    for (int k0 = 0; k0 < DIM; k0 += 32) {
        bf16x8 av0 = *(const bf16x8*)(agp + k0);
        bf16x8 av1 = *(const bf16x8*)(agp + k0 + 8);
        *(bf16x8*)&As[w0] = av0;
        *(bf16x8*)&As[w1] = av1;
        __syncthreads();

        int krow = k0 + g * 8;
        bf16x8 bfrag[4];
        #pragma unroll
        for (int n = 0; n < 4; ++n)
            bfrag[n] = *(const bf16x8*)(WT + (size_t)(gcol + n * 16) * 768 + krow);

        bf16x8 afrag[4];
        #pragma unroll
        for (int m = 0; m < 4; ++m)
            afrag[m] = *(const bf16x8*)&As[(((wr * 4 + m) * 4 + g) * 16 + r) * 8];

        #pragma unroll
        for (int m = 0; m < 4; ++m)
            #pragma unroll
            for (int n = 0; n < 4; ++n)
                acc[m][n] = __builtin_amdgcn_mfma_f32_16x16x32_bf16(
                    afrag[m], bfrag[n], acc[m][n], 0, 0, 0);
        __syncthreads();
    }

    float bv[4];
    #pragma unroll
    for (int n = 0; n < 4; ++n) bv[n] = ldf(bias, woff + gcol + n * 16, fb);
    #pragma unroll
    for (int m = 0; m < 4; ++m) {
        #pragma unroll
        for (int n = 0; n < 4; ++n) {
            #pragma unroll
            for (int i = 0; i < 4; ++i) {
                float v = acc[m][n][i] + bv[n];
                size_t row = brow + wr * 64 + m * 16 + g * 4 + i;
                size_t col = bcol + wc * 64 + n * 16 + r;
                if (F32OUT) ((float*)Cout)[row * DIM + col] = v;
                else        ((bfu*)Cout)[row * DIM + col] = f2b(v);
            }
        }
    }
}

// ------------- depthwise conv3d pool (3x3x3, stride 1,2,2, pad 1) + LN -----
// TR=false: out[(bh*NKV + kpos)*64 + lane]   (K layout [bh][kj][d])
// TR=true : out[(bh*64 + lane)*NKV + kpos]   (V^T layout [bh][d][kj])
template<bool TR>
__global__ __launch_bounds__(256) void pool_ln_kernel(
    const bfu* __restrict__ kv, const void* __restrict__ pw,
    const void* __restrict__ lw, const void* __restrict__ lb,
    bfu* __restrict__ out, const int* __restrict__ fl,
    int fpi, int fwi, int fbi) {
    int fp = fl[fpi], fw = fl[fwi], fb = fl[fbi];
    int p = blockIdx.x * 4 + (threadIdx.x >> 6);
    int lane = threadIdx.x & 63;
    int b = p / (NHEADS * NKV);
    int rem = p % (NHEADS * NKV);
    int h = rem / NKV;
    int kpos = rem % NKV;
    int kt = kpos / 49;
    int r2 = kpos % 49;
    int kh = r2 / 7;
    int kw = r2 % 7;
    float acc = 0.f;
    #pragma unroll
    for (int dt = 0; dt < 3; ++dt) {
        int tt = kt + dt - 1;
        if (tt < 0 || tt >= 8) continue;
        #pragma unroll
        for (int dh = 0; dh < 3; ++dh) {
            int hh = kh * 2 + dh - 1;
            if (hh < 0 || hh >= 14) continue;
            #pragma unroll
            for (int dw = 0; dw < 3; ++dw) {
                int ww = kw * 2 + dw - 1;
                if (ww < 0 || ww >= 14) continue;
                int n = (tt * 14 + hh) * 14 + ww;
                float in = b2f(kv[(size_t)(b * NQ + n) * DIM + h * HD + lane]);
                acc += in * ldf(pw, lane * 27 + dt * 9 + dh * 3 + dw, fp);
            }
        }
    }
    float s = acc, sq = acc * acc;
    #pragma unroll
    for (int o = 1; o < 64; o <<= 1) { s += __shfl_xor(s, o); sq += __shfl_xor(sq, o); }
    float mean = s * (1.0f / 64.0f);
    float var = sq * (1.0f / 64.0f) - mean * mean;
    float rs = rsqrtf(fmaxf(var, 0.0f) + LN_EPS);
    float v = (acc - mean) * rs * ldf(lw, lane, fw) + ldf(lb, lane, fb);
    int bh = b * NHEADS + h;
    if (TR) out[((size_t)bh * HD + lane) * NKV + kpos] = f2b(v);
    else    out[((size_t)bh * NKV + kpos) * HD + lane] = f2b(v);
}

// ---- MFMA flash attention: block = 4 waves x 16 q-rows, kv tiles of 32 ----
// Bias dots: row-per-thread-quad from registers vs LDS Rl. Softmax: fixed
// shift exp(S-8) (|S| <~ 4 by construction), per-lane sum, one final reduce.
__global__ __launch_bounds__(256) void attn_mfma_kernel(
    const bfu* __restrict__ qb, const bfu* __restrict__ kp,
    const bfu* __restrict__ vt, const void* __restrict__ rpt,
    const void* __restrict__ rph, const void* __restrict__ rpw,
    bfu* __restrict__ ao, const int* __restrict__ fl) {
    int fh = fl[13], fwF = fl[14], ft = fl[15];
    // layout: Rl[69][68] f32 @0 (18768) | bsT[64][8] @18768 (2048) |
    //         bsD[64][14] @20816 (3584)  -> total 24400
    // overlays after phase 2 (Rl dead): bsHW[64][52] @0 (13312) |
    //         Pl[4][16][40] bfu @13312 (ends 18432 <= 18768 ok)
    __shared__ __align__(16) unsigned char smem[24400];
    float (*Rl)[68]   = reinterpret_cast<float(*)[68]>(smem);
    float (*bsT)[8]   = reinterpret_cast<float(*)[8]>(smem + 18768);
    float (*bsD)[14]  = reinterpret_cast<float(*)[14]>(smem + 20816);
    float (*bsHW)[52] = reinterpret_cast<float(*)[52]>(smem);
    bfu   (*Pl)[16][40] = reinterpret_cast<bfu(*)[16][40]>(smem + 13312);

    int t = threadIdx.x;
    int l = t & 63, w = t >> 6;
    int g = l >> 4, r = l & 15;
    int blk = blockIdx.x;
    int qt = blk % 25, bh = blk / 25;
    int h = bh % NHEADS, b = bh / NHEADS;
    int rowbase = qt * 64;
    int qw = rowbase + w * 16;

    // ---- phase 1: stage R tables into LDS; q slice into registers ----
    for (int id = t; id < 69 * 64; id += 256) {        // R_all = [rpt;rph;rpw]
        int j = id >> 6, c = id & 63;
        const void* R; int row, rfl;
        if (j < 15)      { R = rpt; row = j;      rfl = ft; }
        else if (j < 42) { R = rph; row = j - 15; rfl = fh; }
        else             { R = rpw; row = j - 42; rfl = fwF; }
        Rl[j][c] = ldf(R, (size_t)row * HD + c, rfl);
    }
    // quad layout: row rr = t>>2, channel slice sub = t&3 (16 channels)
    int rr = t >> 2, sub = t & 3;
    int nqr = rowbase + rr;
    int nqc = (nqr < NQ) ? nqr : (NQ - 1);             // clamp (garbage rows unread)
    float qv16[16];
    {
        const bfu* qrow = qb + (size_t)(b * NQ + nqc) * DIM + h * HD + sub * 16;
        #pragma unroll
        for (int c4 = 0; c4 < 4; ++c4) {
            ushort4 u = *(const ushort4*)(qrow + c4 * 4);
            qv16[c4 * 4 + 0] = b2f(u.x);
            qv16[c4 * 4 + 1] = b2f(u.y);
            qv16[c4 * 4 + 2] = b2f(u.z);
            qv16[c4 * 4 + 3] = b2f(u.w);
        }
    }
    __syncthreads();

    // ---- phase 2: 22 rel-pos dots per row, quad-parallel ----
    {
        int tq = nqc / 196, hq = (nqc % 196) / 14, wq = nqc % 14;
        #pragma unroll
        for (int idx = 0; idx < 22; ++idx) {
            int j;
            if (idx < 8)       j = tq - idx + 7;                  // rpt 0..14
            else if (idx < 15) j = 15 + hq - 2 * (idx - 8) + 12;  // rph 15..41
            else               j = 42 + wq - 2 * (idx - 15) + 12; // rpw 42..68
            float part = 0.f;
            #pragma unroll
            for (int c = 0; c < 16; c += 4) {
                float4 rv = *(const float4*)&Rl[j][sub * 16 + c];
                part += qv16[c] * rv.x + qv16[c + 1] * rv.y
                      + qv16[c + 2] * rv.z + qv16[c + 3] * rv.w;
            }
            part += __shfl_xor(part, 1);
            part += __shfl_xor(part, 2);
            if (sub == 0) {
                if (idx < 8) bsT[rr][idx] = part;
                else         bsD[rr][idx - 8] = part;
            }
        }
    }
    __syncthreads();

    // ---- phase 3: combine h+w biases (bsHW overlays dead Rl) ----
    for (int id = t; id < 64 * 49; id += 256) {
        int rrj = id / 49, r2 = id - rrj * 49;
        bsHW[rrj][r2] = bsD[rrj][r2 / 7] + bsD[rrj][7 + r2 % 7];
    }
    __syncthreads();

    if (qw >= NQ) return;                // tail waves exit after all barriers

    size_t qgrow = (size_t)(b * NQ + qw + r) * DIM + h * HD;
    bf16x8 aq0 = *(const bf16x8*)(qb + qgrow + g * 8);
    bf16x8 aq1 = *(const bf16x8*)(qb + qgrow + 32 + g * 8);

    f32x4 o0, o1, o2, o3;
    #pragma unroll
    for (int i = 0; i < 4; ++i) { o0[i] = 0.f; o1[i] = 0.f; o2[i] = 0.f; o3[i] = 0.f; }
    float lrp[4] = {0.f, 0.f, 0.f, 0.f};   // per-lane partial softmax sums

    const bfu* kbase = kp + (size_t)bh * NKV * HD;
    const bfu* vbase = vt + (size_t)bh * HD * NKV;
    f32x4 zero;
    #pragma unroll
    for (int i = 0; i < 4; ++i) zero[i] = 0.f;

    for (int kt0 = 0; kt0 < NKV; kt0 += 32) {
        // ---- QK^T: 4 mfma ----
        f32x4 s0 = zero, s1 = zero;
        {
            const bfu* k0 = kbase + (size_t)(kt0 + r) * HD + g * 8;
            const bfu* k1 = kbase + (size_t)(kt0 + 16 + r) * HD + g * 8;
            bf16x8 kf;
            kf = *(const bf16x8*)(k0);
            s0 = __builtin_amdgcn_mfma_f32_16x16x32_bf16(aq0, kf, s0, 0, 0, 0);
            kf = *(const bf16x8*)(k0 + 32);
            s0 = __builtin_amdgcn_mfma_f32_16x16x32_bf16(aq1, kf, s0, 0, 0, 0);
            kf = *(const bf16x8*)(k1);
            s1 = __builtin_amdgcn_mfma_f32_16x16x32_bf16(aq0, kf, s1, 0, 0, 0);
            kf = *(const bf16x8*)(k1 + 32);
            s1 = __builtin_amdgcn_mfma_f32_16x16x32_bf16(aq1, kf, s1, 0, 0, 0);
        }
        // ---- scale + rel-pos bias + tail mask (both halves) ----
        int kj0 = kt0 + r, kj1 = kt0 + 16 + r;
        bool msk0 = (kj0 >= NKV);
        bool msk1 = (kj1 >= NKV);
        int kj0c = msk0 ? (NKV - 1) : kj0;
        int kj1c = msk1 ? (NKV - 1) : kj1;
        int kt_0 = kj0c / 49, r2_0 = kj0c - kt_0 * 49;
        int kt_1 = kj1c / 49, r2_1 = kj1c - kt_1 * 49;
        // ---- fixed-shift softmax: P = exp(S - 8); per-lane sum only ----
        #pragma unroll
        for (int i = 0; i < 4; ++i) {
            int br = w * 16 + 4 * g + i;
            float v0 = s0[i] * 0.125f + bsT[br][kt_0] + bsHW[br][r2_0];
            float v1 = s1[i] * 0.125f + bsT[br][kt_1] + bsHW[br][r2_1];
            float p0 = msk0 ? 0.f : b2f(f2b(__expf(v0 - 8.0f)));
            float p1 = msk1 ? 0.f : b2f(f2b(__expf(v1 - 8.0f)));
            lrp[i] += p0 + p1;
            s0[i] = p0; s1[i] = p1;
        }
        // ---- P transpose through per-wave LDS tile ----
        #pragma unroll
        for (int i = 0; i < 4; ++i) {
            Pl[w][4 * g + i][r]      = f2b(s0[i]);
            Pl[w][4 * g + i][16 + r] = f2b(s1[i]);
        }
        bf16x8 pf = *(const bf16x8*)&Pl[w][r][8 * g];
        // ---- PV: 4 mfma, V^T rows are 16B-contiguous in kj ----
        const bfu* vb0 = vbase + (size_t)r * NKV + kt0 + 8 * g;
        bf16x8 vf;
        vf = *(const bf16x8*)(vb0);
        o0 = __builtin_amdgcn_mfma_f32_16x16x32_bf16(pf, vf, o0, 0, 0, 0);
        vf = *(const bf16x8*)(vb0 + 16 * NKV);
        o1 = __builtin_amdgcn_mfma_f32_16x16x32_bf16(pf, vf, o1, 0, 0, 0);
        vf = *(const bf16x8*)(vb0 + 32 * NKV);
        o2 = __builtin_amdgcn_mfma_f32_16x16x32_bf16(pf, vf, o2, 0, 0, 0);
        vf = *(const bf16x8*)(vb0 + 48 * NKV);
        o3 = __builtin_amdgcn_mfma_f32_16x16x32_bf16(pf, vf, o3, 0, 0, 0);
    }

    // ---- epilogue: reduce sums, normalize, +residual q, store ----
    #pragma unroll
    for (int i = 0; i < 4; ++i) {
        float lsum = lrp[i];
        lsum += __shfl_xor(lsum, 1);
        lsum += __shfl_xor(lsum, 2);
        lsum += __shfl_xor(lsum, 4);
        lsum += __shfl_xor(lsum, 8);
        float inv = 1.f / lsum;
        size_t orow = (size_t)(b * NQ + qw + 4 * g + i) * DIM + h * HD + r;
        ao[orow]      = f2b(o0[i] * inv + b2f(qb[orow]));
        ao[orow + 16] = f2b(o1[i] * inv + b2f(qb[orow + 16]));
        ao[orow + 32] = f2b(o2[i] * inv + b2f(qb[orow + 32]));
        ao[orow + 48] = f2b(o3[i] * inv + b2f(qb[orow + 48]));
    }
}

extern "C" void kernel_launch(void* const* d_in, const int* in_sizes, int n_in,
                              void* d_out, int out_size, void* d_ws, size_t ws_size,
                              hipStream_t stream) {
    Ptrs ptrs;
    for (int i = 0; i < 16; ++i) ptrs.p[i] = d_in[i];
    const void* x      = d_in[0];
    const void* ln_w   = d_in[1];
    const void* ln_b   = d_in[2];
    const void* qkv_w  = d_in[3];
    const void* qkv_b  = d_in[4];
    const void* proj_w = d_in[5];
    const void* proj_b = d_in[6];
    const void* poolk_w = d_in[7];
    const void* poolv_w = d_in[8];
    const void* rph    = d_in[13];
    const void* rpw    = d_in[14];
    const void* rpt    = d_in[15];

    bfu* ws = (bfu*)d_ws;
    bfu* A  = ws;                       // 4,816,896: xn, later attention out
    bfu* Bf = ws + 4816896;             // 4,816,896: k / v / q projections
    bfu* kp = ws + 9633792;             // 1,204,224: K [bh][kj][d]; later WT_proj
    bfu* vt = ws + 10838016;            // 1,204,224: V^T [bh][d][kj]
    int* flags = (int*)(ws + 12042240); // 64 bytes
    float* out = (float*)d_out;
    bfu* WTq = (bfu*)d_out;             // 2304x768 bf16 W^T, dead before proj GEMM

    probe_kernel<<<16, 64, 0, stream>>>(ptrs, flags);

    ln_kernel<<<BATCH * NQ, 256, 0, stream>>>(x, ln_w, ln_b, A, flags);

    // qkv_w (f32 [768][2304]) -> bf16 W^T [2304][768] in d_out scratch
    wcvt_kernel<<<dim3(36, 12), 256, 0, stream>>>(qkv_w, WTq, 3 * DIM, flags, 3);

    dim3 ggrid(49, 6);
    // k slice (cols 768..1535)
    gemm_mfma_kernel<false><<<ggrid, 256, 0, stream>>>(A, WTq + (size_t)DIM * 768, qkv_b, Bf, DIM, flags, 4);
    pool_ln_kernel<false><<<4704, 256, 0, stream>>>(Bf, poolk_w, d_in[9], d_in[10], kp, flags, 7, 9, 10);

    // v slice (cols 1536..2303)
    gemm_mfma_kernel<false><<<ggrid, 256, 0, stream>>>(A, WTq + (size_t)(2 * DIM) * 768, qkv_b, Bf, 2 * DIM, flags, 4);
    pool_ln_kernel<true><<<4704, 256, 0, stream>>>(Bf, poolv_w, d_in[11], d_in[12], vt, flags, 8, 11, 12);

    // q slice (cols 0..767)
    gemm_mfma_kernel<false><<<ggrid, 256, 0, stream>>>(A, WTq, qkv_b, Bf, 0, flags, 4);

    attn_mfma_kernel<<<48 * 25, 256, 0, stream>>>(Bf, kp, vt, rpt, rph, rpw, A, flags);

    // proj_w -> bf16 W^T into kp region (kp dead after attn)
    wcvt_kernel<<<dim3(12, 12), 256, 0, stream>>>(proj_w, kp, DIM, flags, 5);

    gemm_mfma_kernel<true><<<ggrid, 256, 0, stream>>>(A, kp, proj_b, out, 0, flags, 6);
}